// Round 6
// baseline (1562.424 us; speedup 1.0000x reference)
//
#include <hip/hip_runtime.h>
#include <cstdint>
#include <cstddef>

#define NPTS 4096
#define BATCH 16

typedef unsigned int uint32;
typedef unsigned short u16;

typedef __attribute__((ext_vector_type(8))) short short8;
typedef __attribute__((ext_vector_type(16))) float float16;

__device__ __forceinline__ u16 f2bf(float f) {
  uint32 u = __float_as_uint(f);
  u = (u + 0x7fffu + ((u >> 16) & 1u)) >> 16;
  return (u16)u;
}
__device__ __forceinline__ float bf2f(u16 h) {
  return __uint_as_float(((uint32)h) << 16);
}

// ---------------- fp32 1x1-conv GEMM (conv1..3, conv7: topk-feeding chain needs fp32 accuracy)
__global__ __launch_bounds__(256) void conv_gemm(
    const float* __restrict__ act, const float* __restrict__ wt,
    const float* __restrict__ rowbias, const float* __restrict__ obias,
    const float* __restrict__ inScale, const float* __restrict__ inShift,
    float* __restrict__ out, float* __restrict__ partials, int C, int O)
{
  __shared__ float As[16][68];
  __shared__ float Ws[16][68];
  __shared__ float redS[64][17];
  __shared__ float redQ[64][17];
  const int b  = blockIdx.z;
  const int o0 = blockIdx.y * 64;
  const int n0 = blockIdx.x * 64;
  const int t  = threadIdx.x;
  const int tx = t & 15, ty = t >> 4;
  float acc[4][4] = {};
  const float* actb = act + ((size_t)b * C) * NPTS;

  for (int k0 = 0; k0 < C; k0 += 16) {
    const int r  = ty;
    const int cs = tx * 4;
    const int k  = k0 + r;
    float4 av = make_float4(0.f, 0.f, 0.f, 0.f);
    if (k < C) {
      av = *(const float4*)(actb + (size_t)k * NPTS + n0 + cs);
      if (inScale) {
        const float scv = inScale[k], shv = inShift[k];
        av.x = fmaxf(fmaf(av.x, scv, shv), 0.f);
        av.y = fmaxf(fmaf(av.y, scv, shv), 0.f);
        av.z = fmaxf(fmaf(av.z, scv, shv), 0.f);
        av.w = fmaxf(fmaf(av.w, scv, shv), 0.f);
      }
    }
    *(float4*)&As[r][cs] = av;

    float4 wv = make_float4(0.f, 0.f, 0.f, 0.f);
    if (k < C) {
      const float* wp = wt + (size_t)k * O;
      const int o = o0 + cs;
      if (o + 3 < O) {
        wv = *(const float4*)&wp[o];
      } else {
        float tmp[4] = {0.f, 0.f, 0.f, 0.f};
        for (int j = 0; j < 4; ++j) if (o + j < O) tmp[j] = wp[o + j];
        wv = make_float4(tmp[0], tmp[1], tmp[2], tmp[3]);
      }
    }
    *(float4*)&Ws[r][cs] = wv;
    __syncthreads();

    const int kmax = (C - k0 < 16) ? (C - k0) : 16;
    for (int kk = 0; kk < kmax; ++kk) {
      float4 a = *(float4*)&As[kk][tx * 4];
      float4 w = *(float4*)&Ws[kk][ty * 4];
      acc[0][0] += w.x * a.x; acc[0][1] += w.x * a.y; acc[0][2] += w.x * a.z; acc[0][3] += w.x * a.w;
      acc[1][0] += w.y * a.x; acc[1][1] += w.y * a.y; acc[1][2] += w.y * a.z; acc[1][3] += w.y * a.w;
      acc[2][0] += w.z * a.x; acc[2][1] += w.z * a.y; acc[2][2] += w.z * a.z; acc[2][3] += w.z * a.w;
      acc[3][0] += w.w * a.x; acc[3][1] += w.w * a.y; acc[3][2] += w.w * a.z; acc[3][3] += w.w * a.w;
    }
    __syncthreads();
  }

  float s[4], q[4];
  for (int i = 0; i < 4; ++i) {
    const int o = o0 + ty * 4 + i;
    s[i] = 0.f; q[i] = 0.f;
    if (o >= O) continue;
    float base = 0.f;
    if (rowbias) base  = rowbias[(size_t)b * O + o];
    if (obias)   base += obias[o];
    float4 v = make_float4(acc[i][0] + base, acc[i][1] + base, acc[i][2] + base, acc[i][3] + base);
    *(float4*)&out[((size_t)b * O + o) * NPTS + n0 + tx * 4] = v;
    s[i] = v.x + v.y + v.z + v.w;
    q[i] = v.x * v.x + v.y * v.y + v.z * v.z + v.w * v.w;
  }

  if (partials) {
    for (int i = 0; i < 4; ++i) { redS[ty * 4 + i][tx] = s[i]; redQ[ty * 4 + i][tx] = q[i]; }
    __syncthreads();
    if (t < 64) {
      float a = 0.f;
      for (int j = 0; j < 16; ++j) a += redS[t][j];
      partials[((size_t)b * O + o0 + t) * 64 + blockIdx.x] = a;
    } else if (t < 128) {
      float a = 0.f;
      for (int j = 0; j < 16; ++j) a += redQ[t - 64][j];
      partials[(size_t)BATCH * O * 64 + ((size_t)b * O + o0 + t - 64) * 64 + blockIdx.x] = a;
    }
  }
}

// ---------------- pack weights (O,Ctot) fp32 -> hi/lo bf16 A-frag order
__global__ __launch_bounds__(256) void pack_wmfma(const float* __restrict__ src,
                                                  u16* __restrict__ ph, u16* __restrict__ pl,
                                                  int O, int Ctot, int cOff, int Csub) {
  int i = blockIdx.x * 256 + threadIdx.x;
  if (i >= O * Csub) return;
  const int KS = Csub >> 4;
  int j    = i & 7;
  int lj   = (i >> 3) & 63;
  int mtks = i >> 9;
  int ks   = mtks % KS;
  int mt   = mtks / KS;
  int o = mt * 32 + (lj & 31);
  int c = ks * 16 + (lj >> 5) * 8 + j;
  float v = src[(size_t)o * Ctot + cOff + c];
  u16 h = f2bf(v);
  ph[i] = h;
  pl[i] = f2bf(v - bf2f(h));
}

// ---------------- MFMA 1x1-conv GEMM (conv4/5/6, continuous path): 128o x 128n tile,
// split-bf16 hi/lo both operands (rel err ~1e-5, fine post-topk).
__global__ __launch_bounds__(256) void conv_mfma(
    const float* __restrict__ act, const u16* __restrict__ wh, const u16* __restrict__ wl,
    const float* __restrict__ rowbias,
    const float* __restrict__ inScale, const float* __restrict__ inShift,
    float* __restrict__ out, float* __restrict__ ps, int C, int O)
{
  __shared__ u16 Bh[4096];   // [2 ks][4 ns][64 lane][8]
  __shared__ u16 Bl[4096];
  const int b  = blockIdx.z;
  const int o0 = blockIdx.y * 128;
  const int n0 = blockIdx.x * 128;
  const int t  = threadIdx.x;
  const int l  = t & 63, wva = t >> 6;
  const int mt = blockIdx.y * 4 + wva;
  const int KS = C >> 4;
  const float* actb = act + ((size_t)b * C) * NPTS;

  float16 acc[4];
#pragma unroll
  for (int ns = 0; ns < 4; ++ns)
#pragma unroll
    for (int r = 0; r < 16; ++r) acc[ns][r] = 0.f;

  const int cq = t >> 5;
  const int nq = t & 31;
  const int nn = n0 + nq * 4;
  const int ksl = cq >> 2, oct = (cq >> 1) & 1, j0 = (cq & 1) * 4;

  for (int k0 = 0; k0 < C; k0 += 32) {
    const int cb = k0 + cq * 4;
    float va[4][4];
#pragma unroll
    for (int i2 = 0; i2 < 4; ++i2) {
      float4 v4 = *(const float4*)(actb + (size_t)(cb + i2) * NPTS + nn);
      if (inScale) {
        const float scv = inScale[cb + i2], shv = inShift[cb + i2];
        v4.x = fmaxf(fmaf(v4.x, scv, shv), 0.f);
        v4.y = fmaxf(fmaf(v4.y, scv, shv), 0.f);
        v4.z = fmaxf(fmaf(v4.z, scv, shv), 0.f);
        v4.w = fmaxf(fmaf(v4.w, scv, shv), 0.f);
      }
      va[i2][0] = v4.x; va[i2][1] = v4.y; va[i2][2] = v4.z; va[i2][3] = v4.w;
    }
    const size_t abase = (((size_t)mt * KS + (k0 >> 4)) * 64 + l) * 8;
    short8 AH0 = *(const short8*)(wh + abase);
    short8 AH1 = *(const short8*)(wh + abase + 512);
    short8 AL0 = *(const short8*)(wl + abase);
    short8 AL1 = *(const short8*)(wl + abase + 512);

    __syncthreads();
#pragma unroll
    for (int d = 0; d < 4; ++d) {
      const int nrel = nq * 4 + d;
      const int ns = nrel >> 5, li = nrel & 31;
      u16 h0 = f2bf(va[0][d]), h1 = f2bf(va[1][d]), h2 = f2bf(va[2][d]), h3 = f2bf(va[3][d]);
      u16 q0 = f2bf(va[0][d] - bf2f(h0));
      u16 q1 = f2bf(va[1][d] - bf2f(h1));
      u16 q2 = f2bf(va[2][d] - bf2f(h2));
      u16 q3 = f2bf(va[3][d] - bf2f(h3));
      const int idx = ((ksl * 4 + ns) * 64 + oct * 32 + li) * 8 + j0;
      *(ushort4*)&Bh[idx] = make_ushort4(h0, h1, h2, h3);
      *(ushort4*)&Bl[idx] = make_ushort4(q0, q1, q2, q3);
    }
    __syncthreads();

#pragma unroll
    for (int ns = 0; ns < 4; ++ns) {
      short8 BH0 = *(const short8*)&Bh[((0 * 4 + ns) * 64 + l) * 8];
      short8 BL0 = *(const short8*)&Bl[((0 * 4 + ns) * 64 + l) * 8];
      acc[ns] = __builtin_amdgcn_mfma_f32_32x32x16_bf16(AH0, BH0, acc[ns], 0, 0, 0);
      acc[ns] = __builtin_amdgcn_mfma_f32_32x32x16_bf16(AL0, BH0, acc[ns], 0, 0, 0);
      acc[ns] = __builtin_amdgcn_mfma_f32_32x32x16_bf16(AH0, BL0, acc[ns], 0, 0, 0);
      short8 BH1 = *(const short8*)&Bh[((1 * 4 + ns) * 64 + l) * 8];
      short8 BL1 = *(const short8*)&Bl[((1 * 4 + ns) * 64 + l) * 8];
      acc[ns] = __builtin_amdgcn_mfma_f32_32x32x16_bf16(AH1, BH1, acc[ns], 0, 0, 0);
      acc[ns] = __builtin_amdgcn_mfma_f32_32x32x16_bf16(AL1, BH1, acc[ns], 0, 0, 0);
      acc[ns] = __builtin_amdgcn_mfma_f32_32x32x16_bf16(AH1, BL1, acc[ns], 0, 0, 0);
    }
  }

  const int col = l & 31, half = l >> 5;
  float sv[16], sq[16];
#pragma unroll
  for (int r = 0; r < 16; ++r) {
    const int o = o0 + wva * 32 + (r & 3) + 8 * (r >> 2) + 4 * half;
    const float base = rowbias ? rowbias[(size_t)b * O + o] : 0.f;
    float s = 0.f, q = 0.f;
#pragma unroll
    for (int ns = 0; ns < 4; ++ns) {
      float val = acc[ns][r] + base;
      out[((size_t)b * O + o) * NPTS + n0 + ns * 32 + col] = val;
      s += val; q += val * val;
    }
    sv[r] = s; sq[r] = q;
  }
  if (ps) {
#pragma unroll
    for (int r = 0; r < 16; ++r) {
#pragma unroll
      for (int m = 1; m < 32; m <<= 1) {
        sv[r] += __shfl_xor(sv[r], m, 64);
        sq[r] += __shfl_xor(sq[r], m, 64);
      }
    }
    if (col == 0) {
#pragma unroll
      for (int r = 0; r < 16; ++r) {
        const int o = o0 + wva * 32 + (r & 3) + 8 * (r >> 2) + 4 * half;
        ps[((size_t)b * O + o) * 32 + blockIdx.x] = sv[r];
        ps[(size_t)BATCH * O * 32 + ((size_t)b * O + o) * 32 + blockIdx.x] = sq[r];
      }
    }
  }
}

// ---------------- BN finalize from conv partials (fixed order), NT = n-tiles per (b,o)
__global__ __launch_bounds__(256) void bn_finalize(const float* __restrict__ ps,
                                                   const float* __restrict__ g, const float* __restrict__ be,
                                                   float* __restrict__ scale, float* __restrict__ shift,
                                                   int O, int NT) {
  int c = blockIdx.x * 256 + threadIdx.x;
  if (c >= O) return;
  const float* p2 = ps + (size_t)BATCH * O * NT;
  float s = 0.f, q = 0.f;
  for (int b = 0; b < BATCH; ++b) {
    size_t base = ((size_t)b * O + c) * NT;
    for (int nt = 0; nt < NT; ++nt) { s += ps[base + nt]; q += p2[base + nt]; }
  }
  const float inv = 1.f / 65536.f;
  float m   = s * inv;
  float var = q * inv - m * m;
  float sc  = g[c] * rsqrtf(var + 1e-5f);
  scale[c] = sc;
  shift[c] = be[c] - m * sc;
}

// ---------------- top-32 per (b,c) on RAW h3: register tournament (deterministic)
__global__ __launch_bounds__(256) void topk_kernel(const float* __restrict__ h3,
                                                   int* __restrict__ idxp) {
  __shared__ float wvv[4];
  __shared__ int   wvi[4];
  __shared__ int   bcI;
  const int c = blockIdx.x, b = blockIdx.y;
  const float* src = h3 + ((size_t)b * 256 + c) * NPTS;
  const int t = threadIdx.x;
  float v[16];
  float bv = -INFINITY; int bi = NPTS;
#pragma unroll
  for (int s = 0; s < 16; ++s) {
    v[s] = src[t + 256 * s];
    if (v[s] > bv) { bv = v[s]; bi = t + 256 * s; }
  }
  int* dst = idxp + ((size_t)b * 256 + c) * 32;
  for (int r = 0; r < 32; ++r) {
    float rv = bv; int ri = bi;
#pragma unroll
    for (int off = 32; off; off >>= 1) {
      float ov = __shfl_down(rv, off, 64);
      int   oi = __shfl_down(ri, off, 64);
      if (ov > rv || (ov == rv && oi < ri)) { rv = ov; ri = oi; }
    }
    if ((t & 63) == 0) { wvv[t >> 6] = rv; wvi[t >> 6] = ri; }
    __syncthreads();
    if (t == 0) {
      for (int k = 1; k < 4; ++k)
        if (wvv[k] > rv || (wvv[k] == rv && wvi[k] < ri)) { rv = wvv[k]; ri = wvi[k]; }
      dst[r] = ri;
      bcI = ri;
    }
    __syncthreads();
    const int wi_ = bcI;
    if ((wi_ & 255) == t) {
      const int slot = wi_ >> 8;
#pragma unroll
      for (int s = 0; s < 16; ++s) if (s == slot) v[s] = -INFINITY;
      bv = -INFINITY; bi = NPTS;
#pragma unroll
      for (int s = 0; s < 16; ++s) if (v[s] > bv) { bv = v[s]; bi = t + 256 * s; }
    }
  }
}

// ---------------- transpose h3 (B,C,N) -> h3T (B,N,C), applying BN scale/shift
__global__ __launch_bounds__(256) void transpose_h3(const float* __restrict__ h3,
                                                    float* __restrict__ h3T,
                                                    const float* __restrict__ sc,
                                                    const float* __restrict__ sh) {
  __shared__ float tile[32][33];
  const int b = blockIdx.z;
  const int n0 = blockIdx.x * 32, c0 = blockIdx.y * 32;
  const int tx = threadIdx.x & 31, ty = threadIdx.x >> 5;
  const float* src = h3 + (size_t)b * 256 * NPTS;
  for (int j = 0; j < 4; ++j)
    tile[ty + j * 8][tx] = src[(size_t)(c0 + ty + j * 8) * NPTS + n0 + tx];
  __syncthreads();
  float* dst = h3T + (size_t)b * NPTS * 256;
  const float scv = sc[c0 + tx], shv = sh[c0 + tx];
  for (int j = 0; j < 4; ++j)
    dst[(size_t)(n0 + ty + j * 8) * 256 + c0 + tx] = fmaf(tile[tx][ty + j * 8], scv, shv);
}

// ---------------- transpose w8 (o,c,w) -> w8t (w,o,c)
__global__ __launch_bounds__(256) void transpose_w8(const float* __restrict__ w8,
                                                    float* __restrict__ w8t) {
  __shared__ float tile[64][65];
  const int m0 = blockIdx.x * 64, w0 = blockIdx.y * 64;
  const int tx = threadIdx.x & 63, ty = threadIdx.x >> 6;
  for (int j = 0; j < 16; ++j)
    tile[ty + j * 4][tx] = w8[(size_t)(m0 + ty + j * 4) * 256 + w0 + tx];
  __syncthreads();
  for (int j = 0; j < 16; ++j)
    w8t[(size_t)(w0 + ty + j * 4) * 65536 + m0 + tx] = tile[tx][ty + j * 4];
}

// ---------------- pack w8t (w,o,c) -> hi/lo bf16 A-frag order
__global__ __launch_bounds__(256) void pack_w8(const float* __restrict__ w8t,
                                               u16* __restrict__ w8h, u16* __restrict__ w8l) {
  size_t i = (size_t)blockIdx.x * 256 + threadIdx.x;
  int j  = (int)(i & 7);
  int lj = (int)((i >> 3) & 63);
  int ks = (int)((i >> 9) & 15);
  int mt = (int)((i >> 13) & 7);
  int w  = (int)(i >> 16);
  int o  = mt * 32 + (lj & 31);
  int c  = ks * 16 + (lj >> 5) * 8 + j;
  float v = w8t[((size_t)w << 16) + (size_t)o * 256 + c];
  u16 h = f2bf(v);
  w8h[i] = h;
  w8l[i] = f2bf(v - bf2f(h));
}

// ---------------- conv8 via MFMA (verified in R4)
#define Y8N (BATCH * 256 * 32)
__global__ __launch_bounds__(256, 1) void conv8_mfma(
    const float* __restrict__ h3T, const u16* __restrict__ w8h,
    const u16* __restrict__ w8l, const int* __restrict__ idxp,
    float* __restrict__ y8p)
{
  __shared__ u16 G[2][8192];
  const int wg = blockIdx.x;
  const int oq = blockIdx.y;
  const int bg = blockIdx.z;
  const int t  = threadIdx.x;
  const int l  = t & 63, wv = t >> 6;
  const int mt = oq * 4 + wv;

  float16 accH[4], accL[4];
  for (int i = 0; i < 4; ++i)
    for (int r = 0; r < 16; ++r) { accH[i][r] = 0.f; accL[i][r] = 0.f; }

  short8 ah[16], al[16];
  const int hrow  = t >> 3;
  const int cbase = (t & 7) * 32;
  float4 g4[8];

  auto issueG = [&](int step) {
    int wi = step >> 2, bi = step & 3;
    int w = wg * 8 + wi;
    int b = bg * 4 + bi;
    int n = idxp[((size_t)b * 256 + w) * 32 + hrow];
    const float* src = h3T + ((size_t)b * NPTS + n) * 256 + cbase;
#pragma unroll
    for (int j = 0; j < 8; ++j) g4[j] = *(const float4*)&src[j * 4];
  };
  auto writeG = [&](int buf) {
#pragma unroll
    for (int a = 0; a < 4; ++a) {
      int c8 = (cbase >> 3) + a;
      int ks = c8 >> 1;
      int lp = hrow + (c8 & 1) * 32;
      float4 v0 = g4[a * 2], v1 = g4[a * 2 + 1];
      uint32 u0 = (uint32)f2bf(v0.x) | ((uint32)f2bf(v0.y) << 16);
      uint32 u1 = (uint32)f2bf(v0.z) | ((uint32)f2bf(v0.w) << 16);
      uint32 u2 = (uint32)f2bf(v1.x) | ((uint32)f2bf(v1.y) << 16);
      uint32 u3 = (uint32)f2bf(v1.z) | ((uint32)f2bf(v1.w) << 16);
      *(uint4*)&G[buf][((size_t)ks * 64 + lp) * 8] = make_uint4(u0, u1, u2, u3);
    }
  };

  issueG(0); writeG(0);
  __syncthreads();

  for (int wi = 0; wi < 8; ++wi) {
    const int w = wg * 8 + wi;
    {
      const size_t base = (((size_t)w * 8 + mt) * 16) * 512 + (size_t)l * 8;
#pragma unroll
      for (int ks = 0; ks < 16; ++ks) {
        ah[ks] = *(const short8*)(w8h + base + ks * 512);
        al[ks] = *(const short8*)(w8l + base + ks * 512);
      }
    }
#pragma unroll
    for (int bi = 0; bi < 4; ++bi) {
      const int step = wi * 4 + bi;
      const int cur = bi & 1;
      if (step < 31) issueG(step + 1);
      const u16* Gc = G[cur];
#pragma unroll
      for (int ks = 0; ks < 16; ++ks) {
        short8 bf = *(const short8*)&Gc[((size_t)ks * 64 + l) * 8];
        accH[bi] = __builtin_amdgcn_mfma_f32_32x32x16_bf16(ah[ks], bf, accH[bi], 0, 0, 0);
        accL[bi] = __builtin_amdgcn_mfma_f32_32x32x16_bf16(al[ks], bf, accL[bi], 0, 0, 0);
      }
      if (step < 31) writeG(1 - cur);
      __syncthreads();
    }
  }

  const int h = l & 31;
  const int rbase = oq * 128 + wv * 32 + 4 * (l >> 5);
#pragma unroll
  for (int bi = 0; bi < 4; ++bi) {
    int b = bg * 4 + bi;
    float* dst = y8p + ((size_t)(wg * BATCH + b) * 256) * 32;
#pragma unroll
    for (int r = 0; r < 16; ++r) {
      int o = rbase + (r & 3) + 8 * (r >> 2);
      dst[(size_t)o * 32 + h] = accH[bi][r] + accL[bi][r];
    }
  }
}

// ---------------- y8 = b8 + fixed-order sum of 32 w-group partials
__global__ __launch_bounds__(256) void y8_reduce(const float* __restrict__ y8p,
                                                 const float* __restrict__ b8,
                                                 float* __restrict__ y8) {
  int i = blockIdx.x * 256 + threadIdx.x;
  float s = b8[(i >> 5) & 255];
#pragma unroll
  for (int p = 0; p < 32; ++p) s += y8p[(size_t)p * Y8N + i];
  y8[i] = s;
}

// ---------------- conv9
__global__ __launch_bounds__(256) void conv9_kernel(const float* __restrict__ y8,
                                                    const float* __restrict__ w9,
                                                    const float* __restrict__ b9,
                                                    float* __restrict__ y9) {
  const int o = blockIdx.x, b = blockIdx.y;
  const float* yb = y8 + (size_t)b * 8192;
  const float* wo = w9 + (size_t)o * 8192;
  float s = 0.f;
  for (int i = threadIdx.x * 4; i < 8192; i += 1024) {
    float4 v = *(const float4*)&yb[i];
    float4 u = *(const float4*)&wo[i];
    s += v.x * u.x + v.y * u.y + v.z * u.z + v.w * u.w;
  }
  for (int off = 32; off; off >>= 1) s += __shfl_down(s, off, 64);
  __shared__ float ls[4];
  const int wid = threadIdx.x >> 6;
  if ((threadIdx.x & 63) == 0) ls[wid] = s;
  __syncthreads();
  if (threadIdx.x == 0) y9[(size_t)b * 256 + o] = ls[0] + ls[1] + ls[2] + ls[3] + b9[o];
}

// ---------------- cvec[b,o] = sum_c w4[o,c] * y9[b,c]
__global__ __launch_bounds__(256) void cvec_kernel(const float* __restrict__ y9,
                                                   const float* __restrict__ w4,
                                                   float* __restrict__ cvec) {
  int tid = blockIdx.x * 256 + threadIdx.x;
  if (tid >= BATCH * 512) return;
  const int b = tid >> 9, o = tid & 511;
  const float* row = w4 + (size_t)o * 320;
  const float* yb  = y9 + (size_t)b * 256;
  float s = 0.f;
  for (int c = 0; c < 256; c += 4) {
    float4 u = *(const float4*)&row[c];
    s += u.x * yb[c] + u.y * yb[c + 1] + u.z * yb[c + 2] + u.w * yb[c + 3];
  }
  cvec[(size_t)b * 512 + o] = s;
}

// ---------------- small weight transpose (fp32 conv path)
__global__ __launch_bounds__(256) void transpose_w(const float* __restrict__ src,
                                                   float* __restrict__ dst,
                                                   int O, int Ctot, int cOff, int Csub) {
  int i = blockIdx.x * 256 + threadIdx.x;
  if (i >= O * Csub) return;
  int c = i / O, o = i - c * O;
  dst[(size_t)c * O + o] = src[(size_t)o * Ctot + cOff + c];
}

// ---------------- final tanh
__global__ __launch_bounds__(256) void tanh_out(const float* __restrict__ raw,
                                                float* __restrict__ out) {
  int i = blockIdx.x * 256 + threadIdx.x;
  if (i < BATCH * 3 * NPTS) out[i] = tanhf(raw[i]);
}

extern "C" void kernel_launch(void* const* d_in, const int* in_sizes, int n_in,
                              void* d_out, int out_size, void* d_ws, size_t ws_size,
                              hipStream_t stream) {
  (void)in_sizes; (void)n_in; (void)ws_size; (void)out_size;
  const float* x   = (const float*)d_in[0];
  const float* w1  = (const float*)d_in[1];
  const float* g1  = (const float*)d_in[3];
  const float* be1 = (const float*)d_in[4];
  const float* w2  = (const float*)d_in[5];
  const float* g2  = (const float*)d_in[7];
  const float* be2 = (const float*)d_in[8];
  const float* w3  = (const float*)d_in[9];
  const float* g3  = (const float*)d_in[11];
  const float* be3 = (const float*)d_in[12];
  const float* w4  = (const float*)d_in[13];
  const float* g4  = (const float*)d_in[15];
  const float* be4 = (const float*)d_in[16];
  const float* w5  = (const float*)d_in[17];
  const float* g5  = (const float*)d_in[19];
  const float* be5 = (const float*)d_in[20];
  const float* w6  = (const float*)d_in[21];
  const float* g6  = (const float*)d_in[23];
  const float* be6 = (const float*)d_in[24];
  const float* w7  = (const float*)d_in[25];
  const float* b7  = (const float*)d_in[26];
  const float* w8  = (const float*)d_in[27];
  const float* b8  = (const float*)d_in[28];
  const float* w9  = (const float*)d_in[29];
  const float* b9  = (const float*)d_in[30];

  char* ws = (char*)d_ws;
  size_t off = 0;
  auto alloc = [&](size_t bytes) -> void* {
    void* p = ws + off;
    off += (bytes + 255) & ~(size_t)255;
    return p;
  };
  float* Q1  = (float*)alloc((size_t)BATCH * 64  * NPTS * 4);  // h1 / raw7
  float* Q2  = (float*)alloc((size_t)BATCH * 128 * NPTS * 4);  // h2 / y8p / h4 base / h6
  float* Q3  = (float*)alloc((size_t)BATCH * 256 * NPTS * 4);  // h3 (raw)
  float* Q4  = (float*)alloc((size_t)BATCH * 256 * NPTS * 4);  // w8t (early) / h3T
  float* Q5  = (float*)alloc((size_t)BATCH * 256 * NPTS * 4);  // w8h+w8l (early) / h5
  int*   idx  = (int*)alloc((size_t)BATCH * 256 * 32 * 4);
  float* y8   = (float*)alloc((size_t)Y8N * 4);
  float* y9   = (float*)alloc((size_t)BATCH * 256 * 4);
  float* cvec = (float*)alloc((size_t)BATCH * 512 * 4);
  float* ps   = (float*)alloc((size_t)2 * BATCH * 512 * 64 * 4);
  float* scb  = (float*)alloc((size_t)6 * 1024 * 4);
  float* w1t  = (float*)alloc(4   * 64  * 4);
  float* w2t  = (float*)alloc(64  * 128 * 4);
  float* w3t  = (float*)alloc(128 * 256 * 4);
  float* w7t  = (float*)alloc(128 * 3   * 4);
  u16* ph4 = (u16*)alloc(512 * 64  * 2);  u16* pl4 = (u16*)alloc(512 * 64  * 2);
  u16* ph5 = (u16*)alloc(256 * 512 * 2);  u16* pl5 = (u16*)alloc(256 * 512 * 2);
  u16* ph6 = (u16*)alloc(128 * 256 * 2);  u16* pl6 = (u16*)alloc(128 * 256 * 2);

  float* w8t = Q4;                            // fp32, dead before h3T
  u16*   w8h = (u16*)Q5;                      // 33.5MB
  u16*   w8l = (u16*)Q5 + (size_t)16777216;   // dead before h5
  float* y8p = Q2;                            // dead before h4
  float* h4  = Q2;                            // 134MB spans Q2..Q4 head (all dead then)

  float* sc[6]; float* sh[6];
  for (int i = 0; i < 6; ++i) { sc[i] = scb + i * 1024; sh[i] = scb + i * 1024 + 512; }

  // ---- weight preprocessing
  transpose_w<<<(4 * 64 + 255) / 256,   256, 0, stream>>>(w1, w1t, 64, 4, 0, 4);
  transpose_w<<<(64 * 128 + 255) / 256, 256, 0, stream>>>(w2, w2t, 128, 64, 0, 64);
  transpose_w<<<(128 * 256 + 255) / 256,256, 0, stream>>>(w3, w3t, 256, 128, 0, 128);
  transpose_w<<<(128 * 3 + 255) / 256,  256, 0, stream>>>(w7, w7t, 3, 128, 0, 128);
  pack_wmfma<<<(512 * 64  + 255) / 256, 256, 0, stream>>>(w4, ph4, pl4, 512, 320, 256, 64);
  pack_wmfma<<<(256 * 512 + 255) / 256, 256, 0, stream>>>(w5, ph5, pl5, 256, 512, 0,   512);
  pack_wmfma<<<(128 * 256 + 255) / 256, 256, 0, stream>>>(w6, ph6, pl6, 128, 256, 0,   256);
  transpose_w8<<<dim3(1024, 4), 256, 0, stream>>>(w8, w8t);
  pack_w8<<<65536, 256, 0, stream>>>(w8t, w8h, w8l);

  // ---- conv1..3 fp32 (topk-feeding chain: fp32 accuracy required for rank stability)
  conv_gemm<<<dim3(64, 1, BATCH), 256, 0, stream>>>(x, w1t, nullptr, nullptr, nullptr, nullptr, Q1, ps, 4, 64);
  bn_finalize<<<1, 256, 0, stream>>>(ps, g1, be1, sc[0], sh[0], 64, 64);
  conv_gemm<<<dim3(64, 2, BATCH), 256, 0, stream>>>(Q1, w2t, nullptr, nullptr, sc[0], sh[0], Q2, ps, 64, 128);
  bn_finalize<<<1, 256, 0, stream>>>(ps, g2, be2, sc[1], sh[1], 128, 64);
  conv_gemm<<<dim3(64, 4, BATCH), 256, 0, stream>>>(Q2, w3t, nullptr, nullptr, sc[1], sh[1], Q3, ps, 128, 256);
  bn_finalize<<<1, 256, 0, stream>>>(ps, g3, be3, sc[2], sh[2], 256, 64);

  // ---- softpool
  topk_kernel<<<dim3(256, BATCH), 256, 0, stream>>>(Q3, idx);
  transpose_h3<<<dim3(NPTS / 32, 8, BATCH), 256, 0, stream>>>(Q3, Q4, sc[2], sh[2]);

  // ---- conv8 -> conv9 -> cvec
  conv8_mfma<<<dim3(32, 2, 4), 256, 0, stream>>>(Q4, w8h, w8l, idx, y8p);
  y8_reduce<<<Y8N / 256, 256, 0, stream>>>(y8p, b8, y8);
  conv9_kernel<<<dim3(256, BATCH), 256, 0, stream>>>(y8, w9, b9, y9);
  cvec_kernel<<<(BATCH * 512 + 255) / 256, 256, 0, stream>>>(y9, w4, cvec);

  // ---- conv4 (MFMA, rowbias=cvec, input h1 raw + BN1+relu)
  conv_mfma<<<dim3(32, 4, BATCH), 256, 0, stream>>>(Q1, ph4, pl4, cvec, sc[0], sh[0], h4, ps, 64, 512);
  bn_finalize<<<2, 256, 0, stream>>>(ps, g4, be4, sc[3], sh[3], 512, 32);
  // ---- conv5 (MFMA)
  conv_mfma<<<dim3(32, 2, BATCH), 256, 0, stream>>>(h4, ph5, pl5, nullptr, sc[3], sh[3], Q5, ps, 512, 256);
  bn_finalize<<<1, 256, 0, stream>>>(ps, g5, be5, sc[4], sh[4], 256, 32);
  // ---- conv6 (MFMA)
  conv_mfma<<<dim3(32, 1, BATCH), 256, 0, stream>>>(Q5, ph6, pl6, nullptr, sc[4], sh[4], Q2, ps, 256, 128);
  bn_finalize<<<1, 256, 0, stream>>>(ps, g6, be6, sc[5], sh[5], 128, 32);
  // ---- conv7 (fp32, +b7, fused BN6+relu) -> tanh
  conv_gemm<<<dim3(64, 1, BATCH), 256, 0, stream>>>(Q2, w7t, nullptr, b7, sc[5], sh[5], Q1, nullptr, 128, 3);
  tanh_out<<<(BATCH * 3 * NPTS) / 256, 256, 0, stream>>>(Q1, (float*)d_out);
}

// Round 7
// 783.564 us; speedup vs baseline: 1.9940x; 1.9940x over previous
//
#include <hip/hip_runtime.h>
#include <cstdint>
#include <cstddef>

#define NPTS 4096
#define BATCH 16

typedef unsigned int uint32;
typedef unsigned short u16;

typedef __attribute__((ext_vector_type(8))) short short8;
typedef __attribute__((ext_vector_type(16))) float float16;

__device__ __forceinline__ u16 f2bf(float f) {
  uint32 u = __float_as_uint(f);
  u = (u + 0x7fffu + ((u >> 16) & 1u)) >> 16;
  return (u16)u;
}
__device__ __forceinline__ float bf2f(u16 h) {
  return __uint_as_float(((uint32)h) << 16);
}

// ---------------- fp32 1x1-conv GEMM (conv1..3, conv7: topk-feeding chain needs fp32 accuracy)
__global__ __launch_bounds__(256) void conv_gemm(
    const float* __restrict__ act, const float* __restrict__ wt,
    const float* __restrict__ rowbias, const float* __restrict__ obias,
    const float* __restrict__ inScale, const float* __restrict__ inShift,
    float* __restrict__ out, float* __restrict__ partials, int C, int O)
{
  __shared__ float As[16][68];
  __shared__ float Ws[16][68];
  __shared__ float redS[64][17];
  __shared__ float redQ[64][17];
  const int b  = blockIdx.z;
  const int o0 = blockIdx.y * 64;
  const int n0 = blockIdx.x * 64;
  const int t  = threadIdx.x;
  const int tx = t & 15, ty = t >> 4;
  float acc[4][4] = {};
  const float* actb = act + ((size_t)b * C) * NPTS;

  for (int k0 = 0; k0 < C; k0 += 16) {
    const int r  = ty;
    const int cs = tx * 4;
    const int k  = k0 + r;
    float4 av = make_float4(0.f, 0.f, 0.f, 0.f);
    if (k < C) {
      av = *(const float4*)(actb + (size_t)k * NPTS + n0 + cs);
      if (inScale) {
        const float scv = inScale[k], shv = inShift[k];
        av.x = fmaxf(fmaf(av.x, scv, shv), 0.f);
        av.y = fmaxf(fmaf(av.y, scv, shv), 0.f);
        av.z = fmaxf(fmaf(av.z, scv, shv), 0.f);
        av.w = fmaxf(fmaf(av.w, scv, shv), 0.f);
      }
    }
    *(float4*)&As[r][cs] = av;

    float4 wv = make_float4(0.f, 0.f, 0.f, 0.f);
    if (k < C) {
      const float* wp = wt + (size_t)k * O;
      const int o = o0 + cs;
      if (o + 3 < O) {
        wv = *(const float4*)&wp[o];
      } else {
        float tmp[4] = {0.f, 0.f, 0.f, 0.f};
        for (int j = 0; j < 4; ++j) if (o + j < O) tmp[j] = wp[o + j];
        wv = make_float4(tmp[0], tmp[1], tmp[2], tmp[3]);
      }
    }
    *(float4*)&Ws[r][cs] = wv;
    __syncthreads();

    const int kmax = (C - k0 < 16) ? (C - k0) : 16;
    for (int kk = 0; kk < kmax; ++kk) {
      float4 a = *(float4*)&As[kk][tx * 4];
      float4 w = *(float4*)&Ws[kk][ty * 4];
      acc[0][0] += w.x * a.x; acc[0][1] += w.x * a.y; acc[0][2] += w.x * a.z; acc[0][3] += w.x * a.w;
      acc[1][0] += w.y * a.x; acc[1][1] += w.y * a.y; acc[1][2] += w.y * a.z; acc[1][3] += w.y * a.w;
      acc[2][0] += w.z * a.x; acc[2][1] += w.z * a.y; acc[2][2] += w.z * a.z; acc[2][3] += w.z * a.w;
      acc[3][0] += w.w * a.x; acc[3][1] += w.w * a.y; acc[3][2] += w.w * a.z; acc[3][3] += w.w * a.w;
    }
    __syncthreads();
  }

  float s[4], q[4];
  for (int i = 0; i < 4; ++i) {
    const int o = o0 + ty * 4 + i;
    s[i] = 0.f; q[i] = 0.f;
    if (o >= O) continue;
    float base = 0.f;
    if (rowbias) base  = rowbias[(size_t)b * O + o];
    if (obias)   base += obias[o];
    float4 v = make_float4(acc[i][0] + base, acc[i][1] + base, acc[i][2] + base, acc[i][3] + base);
    *(float4*)&out[((size_t)b * O + o) * NPTS + n0 + tx * 4] = v;
    s[i] = v.x + v.y + v.z + v.w;
    q[i] = v.x * v.x + v.y * v.y + v.z * v.z + v.w * v.w;
  }

  if (partials) {
    for (int i = 0; i < 4; ++i) { redS[ty * 4 + i][tx] = s[i]; redQ[ty * 4 + i][tx] = q[i]; }
    __syncthreads();
    if (t < 64) {
      float a = 0.f;
      for (int j = 0; j < 16; ++j) a += redS[t][j];
      partials[((size_t)b * O + o0 + t) * 64 + blockIdx.x] = a;
    } else if (t < 128) {
      float a = 0.f;
      for (int j = 0; j < 16; ++j) a += redQ[t - 64][j];
      partials[(size_t)BATCH * O * 64 + ((size_t)b * O + o0 + t - 64) * 64 + blockIdx.x] = a;
    }
  }
}

// ---------------- pack weights (O,Ctot) fp32 -> hi/lo bf16 A-frag order
__global__ __launch_bounds__(256) void pack_wmfma(const float* __restrict__ src,
                                                  u16* __restrict__ ph, u16* __restrict__ pl,
                                                  int O, int Ctot, int cOff, int Csub) {
  int i = blockIdx.x * 256 + threadIdx.x;
  if (i >= O * Csub) return;
  const int KS = Csub >> 4;
  int j    = i & 7;
  int lj   = (i >> 3) & 63;
  int mtks = i >> 9;
  int ks   = mtks % KS;
  int mt   = mtks / KS;
  int o = mt * 32 + (lj & 31);
  int c = ks * 16 + (lj >> 5) * 8 + j;
  float v = src[(size_t)o * Ctot + cOff + c];
  u16 h = f2bf(v);
  ph[i] = h;
  pl[i] = f2bf(v - bf2f(h));
}

// ---------------- MFMA 1x1-conv GEMM (conv4/5/6, continuous path): 128o x 128n tile,
// split-bf16 hi/lo both operands (rel err ~1e-5, fine post-topk).
__global__ __launch_bounds__(256) void conv_mfma(
    const float* __restrict__ act, const u16* __restrict__ wh, const u16* __restrict__ wl,
    const float* __restrict__ rowbias,
    const float* __restrict__ inScale, const float* __restrict__ inShift,
    float* __restrict__ out, float* __restrict__ ps, int C, int O)
{
  __shared__ u16 Bh[4096];   // [2 ks][4 ns][64 lane][8]
  __shared__ u16 Bl[4096];
  const int b  = blockIdx.z;
  const int o0 = blockIdx.y * 128;
  const int n0 = blockIdx.x * 128;
  const int t  = threadIdx.x;
  const int l  = t & 63, wva = t >> 6;
  const int mt = blockIdx.y * 4 + wva;
  const int KS = C >> 4;
  const float* actb = act + ((size_t)b * C) * NPTS;

  float16 acc[4];
#pragma unroll
  for (int ns = 0; ns < 4; ++ns)
#pragma unroll
    for (int r = 0; r < 16; ++r) acc[ns][r] = 0.f;

  const int cq = t >> 5;
  const int nq = t & 31;
  const int nn = n0 + nq * 4;
  const int ksl = cq >> 2, oct = (cq >> 1) & 1, j0 = (cq & 1) * 4;

  for (int k0 = 0; k0 < C; k0 += 32) {
    const int cb = k0 + cq * 4;
    float va[4][4];
#pragma unroll
    for (int i2 = 0; i2 < 4; ++i2) {
      float4 v4 = *(const float4*)(actb + (size_t)(cb + i2) * NPTS + nn);
      if (inScale) {
        const float scv = inScale[cb + i2], shv = inShift[cb + i2];
        v4.x = fmaxf(fmaf(v4.x, scv, shv), 0.f);
        v4.y = fmaxf(fmaf(v4.y, scv, shv), 0.f);
        v4.z = fmaxf(fmaf(v4.z, scv, shv), 0.f);
        v4.w = fmaxf(fmaf(v4.w, scv, shv), 0.f);
      }
      va[i2][0] = v4.x; va[i2][1] = v4.y; va[i2][2] = v4.z; va[i2][3] = v4.w;
    }
    const size_t abase = (((size_t)mt * KS + (k0 >> 4)) * 64 + l) * 8;
    short8 AH0 = *(const short8*)(wh + abase);
    short8 AH1 = *(const short8*)(wh + abase + 512);
    short8 AL0 = *(const short8*)(wl + abase);
    short8 AL1 = *(const short8*)(wl + abase + 512);

    __syncthreads();
#pragma unroll
    for (int d = 0; d < 4; ++d) {
      const int nrel = nq * 4 + d;
      const int ns = nrel >> 5, li = nrel & 31;
      u16 h0 = f2bf(va[0][d]), h1 = f2bf(va[1][d]), h2 = f2bf(va[2][d]), h3 = f2bf(va[3][d]);
      u16 q0 = f2bf(va[0][d] - bf2f(h0));
      u16 q1 = f2bf(va[1][d] - bf2f(h1));
      u16 q2 = f2bf(va[2][d] - bf2f(h2));
      u16 q3 = f2bf(va[3][d] - bf2f(h3));
      const int idx = ((ksl * 4 + ns) * 64 + oct * 32 + li) * 8 + j0;
      *(ushort4*)&Bh[idx] = make_ushort4(h0, h1, h2, h3);
      *(ushort4*)&Bl[idx] = make_ushort4(q0, q1, q2, q3);
    }
    __syncthreads();

#pragma unroll
    for (int ns = 0; ns < 4; ++ns) {
      short8 BH0 = *(const short8*)&Bh[((0 * 4 + ns) * 64 + l) * 8];
      short8 BL0 = *(const short8*)&Bl[((0 * 4 + ns) * 64 + l) * 8];
      acc[ns] = __builtin_amdgcn_mfma_f32_32x32x16_bf16(AH0, BH0, acc[ns], 0, 0, 0);
      acc[ns] = __builtin_amdgcn_mfma_f32_32x32x16_bf16(AL0, BH0, acc[ns], 0, 0, 0);
      acc[ns] = __builtin_amdgcn_mfma_f32_32x32x16_bf16(AH0, BL0, acc[ns], 0, 0, 0);
      short8 BH1 = *(const short8*)&Bh[((1 * 4 + ns) * 64 + l) * 8];
      short8 BL1 = *(const short8*)&Bl[((1 * 4 + ns) * 64 + l) * 8];
      acc[ns] = __builtin_amdgcn_mfma_f32_32x32x16_bf16(AH1, BH1, acc[ns], 0, 0, 0);
      acc[ns] = __builtin_amdgcn_mfma_f32_32x32x16_bf16(AL1, BH1, acc[ns], 0, 0, 0);
      acc[ns] = __builtin_amdgcn_mfma_f32_32x32x16_bf16(AH1, BL1, acc[ns], 0, 0, 0);
    }
  }

  const int col = l & 31, half = l >> 5;
  float sv[16], sq[16];
#pragma unroll
  for (int r = 0; r < 16; ++r) {
    const int o = o0 + wva * 32 + (r & 3) + 8 * (r >> 2) + 4 * half;
    const float base = rowbias ? rowbias[(size_t)b * O + o] : 0.f;
    float s = 0.f, q = 0.f;
#pragma unroll
    for (int ns = 0; ns < 4; ++ns) {
      float val = acc[ns][r] + base;
      out[((size_t)b * O + o) * NPTS + n0 + ns * 32 + col] = val;
      s += val; q += val * val;
    }
    sv[r] = s; sq[r] = q;
  }
  if (ps) {
#pragma unroll
    for (int r = 0; r < 16; ++r) {
#pragma unroll
      for (int m = 1; m < 32; m <<= 1) {
        sv[r] += __shfl_xor(sv[r], m, 64);
        sq[r] += __shfl_xor(sq[r], m, 64);
      }
    }
    if (col == 0) {
#pragma unroll
      for (int r = 0; r < 16; ++r) {
        const int o = o0 + wva * 32 + (r & 3) + 8 * (r >> 2) + 4 * half;
        ps[((size_t)b * O + o) * 32 + blockIdx.x] = sv[r];
        ps[(size_t)BATCH * O * 32 + ((size_t)b * O + o) * 32 + blockIdx.x] = sq[r];
      }
    }
  }
}

// ---------------- BN finalize: one block per channel, parallel deterministic reduction.
// (R6 post-mortem: 1-block rolled-loop version was latency-serialized at 233 us/call.)
__global__ __launch_bounds__(256) void bn_finalize(const float* __restrict__ ps,
                                                   const float* __restrict__ g, const float* __restrict__ be,
                                                   float* __restrict__ scale, float* __restrict__ shift,
                                                   int O, int NT) {
  const int c = blockIdx.x;
  const int total = BATCH * NT;          // 512 or 1024
  const float* p2 = ps + (size_t)BATCH * O * NT;
  const int t = threadIdx.x;
  float s = 0.f, q = 0.f;
  for (int e = t; e < total; e += 256) {  // <=4 independent iterations
    const int b = e / NT, nt = e - b * NT;
    const size_t a = ((size_t)b * O + c) * NT + nt;
    s += ps[a];
    q += p2[a];
  }
#pragma unroll
  for (int m = 32; m; m >>= 1) {
    s += __shfl_down(s, m, 64);
    q += __shfl_down(q, m, 64);
  }
  __shared__ float lsS[4], lsQ[4];
  const int wid = t >> 6;
  if ((t & 63) == 0) { lsS[wid] = s; lsQ[wid] = q; }
  __syncthreads();
  if (t == 0) {
    s = lsS[0] + lsS[1] + lsS[2] + lsS[3];
    q = lsQ[0] + lsQ[1] + lsQ[2] + lsQ[3];
    const float inv = 1.f / 65536.f;
    float m   = s * inv;
    float var = q * inv - m * m;
    float sc  = g[c] * rsqrtf(var + 1e-5f);
    scale[c] = sc;
    shift[c] = be[c] - m * sc;
  }
}

// ---------------- top-32 per (b,c) on RAW h3: register tournament (deterministic)
__global__ __launch_bounds__(256) void topk_kernel(const float* __restrict__ h3,
                                                   int* __restrict__ idxp) {
  __shared__ float wvv[4];
  __shared__ int   wvi[4];
  __shared__ int   bcI;
  const int c = blockIdx.x, b = blockIdx.y;
  const float* src = h3 + ((size_t)b * 256 + c) * NPTS;
  const int t = threadIdx.x;
  float v[16];
  float bv = -INFINITY; int bi = NPTS;
#pragma unroll
  for (int s = 0; s < 16; ++s) {
    v[s] = src[t + 256 * s];
    if (v[s] > bv) { bv = v[s]; bi = t + 256 * s; }
  }
  int* dst = idxp + ((size_t)b * 256 + c) * 32;
  for (int r = 0; r < 32; ++r) {
    float rv = bv; int ri = bi;
#pragma unroll
    for (int off = 32; off; off >>= 1) {
      float ov = __shfl_down(rv, off, 64);
      int   oi = __shfl_down(ri, off, 64);
      if (ov > rv || (ov == rv && oi < ri)) { rv = ov; ri = oi; }
    }
    if ((t & 63) == 0) { wvv[t >> 6] = rv; wvi[t >> 6] = ri; }
    __syncthreads();
    if (t == 0) {
      for (int k = 1; k < 4; ++k)
        if (wvv[k] > rv || (wvv[k] == rv && wvi[k] < ri)) { rv = wvv[k]; ri = wvi[k]; }
      dst[r] = ri;
      bcI = ri;
    }
    __syncthreads();
    const int wi_ = bcI;
    if ((wi_ & 255) == t) {
      const int slot = wi_ >> 8;
#pragma unroll
      for (int s = 0; s < 16; ++s) if (s == slot) v[s] = -INFINITY;
      bv = -INFINITY; bi = NPTS;
#pragma unroll
      for (int s = 0; s < 16; ++s) if (v[s] > bv) { bv = v[s]; bi = t + 256 * s; }
    }
  }
}

// ---------------- transpose h3 (B,C,N) -> h3T (B,N,C), applying BN scale/shift
__global__ __launch_bounds__(256) void transpose_h3(const float* __restrict__ h3,
                                                    float* __restrict__ h3T,
                                                    const float* __restrict__ sc,
                                                    const float* __restrict__ sh) {
  __shared__ float tile[32][33];
  const int b = blockIdx.z;
  const int n0 = blockIdx.x * 32, c0 = blockIdx.y * 32;
  const int tx = threadIdx.x & 31, ty = threadIdx.x >> 5;
  const float* src = h3 + (size_t)b * 256 * NPTS;
  for (int j = 0; j < 4; ++j)
    tile[ty + j * 8][tx] = src[(size_t)(c0 + ty + j * 8) * NPTS + n0 + tx];
  __syncthreads();
  float* dst = h3T + (size_t)b * NPTS * 256;
  const float scv = sc[c0 + tx], shv = sh[c0 + tx];
  for (int j = 0; j < 4; ++j)
    dst[(size_t)(n0 + ty + j * 8) * 256 + c0 + tx] = fmaf(tile[tx][ty + j * 8], scv, shv);
}

// ---------------- transpose w8 (o,c,w) -> w8t (w,o,c)
__global__ __launch_bounds__(256) void transpose_w8(const float* __restrict__ w8,
                                                    float* __restrict__ w8t) {
  __shared__ float tile[64][65];
  const int m0 = blockIdx.x * 64, w0 = blockIdx.y * 64;
  const int tx = threadIdx.x & 63, ty = threadIdx.x >> 6;
  for (int j = 0; j < 16; ++j)
    tile[ty + j * 4][tx] = w8[(size_t)(m0 + ty + j * 4) * 256 + w0 + tx];
  __syncthreads();
  for (int j = 0; j < 16; ++j)
    w8t[(size_t)(w0 + ty + j * 4) * 65536 + m0 + tx] = tile[tx][ty + j * 4];
}

// ---------------- pack w8t (w,o,c) -> hi/lo bf16 A-frag order
__global__ __launch_bounds__(256) void pack_w8(const float* __restrict__ w8t,
                                               u16* __restrict__ w8h, u16* __restrict__ w8l) {
  size_t i = (size_t)blockIdx.x * 256 + threadIdx.x;
  int j  = (int)(i & 7);
  int lj = (int)((i >> 3) & 63);
  int ks = (int)((i >> 9) & 15);
  int mt = (int)((i >> 13) & 7);
  int w  = (int)(i >> 16);
  int o  = mt * 32 + (lj & 31);
  int c  = ks * 16 + (lj >> 5) * 8 + j;
  float v = w8t[((size_t)w << 16) + (size_t)o * 256 + c];
  u16 h = f2bf(v);
  w8h[i] = h;
  w8l[i] = f2bf(v - bf2f(h));
}

// ---------------- conv8 via MFMA (verified in R4)
#define Y8N (BATCH * 256 * 32)
__global__ __launch_bounds__(256, 1) void conv8_mfma(
    const float* __restrict__ h3T, const u16* __restrict__ w8h,
    const u16* __restrict__ w8l, const int* __restrict__ idxp,
    float* __restrict__ y8p)
{
  __shared__ u16 G[2][8192];
  const int wg = blockIdx.x;
  const int oq = blockIdx.y;
  const int bg = blockIdx.z;
  const int t  = threadIdx.x;
  const int l  = t & 63, wv = t >> 6;
  const int mt = oq * 4 + wv;

  float16 accH[4], accL[4];
  for (int i = 0; i < 4; ++i)
    for (int r = 0; r < 16; ++r) { accH[i][r] = 0.f; accL[i][r] = 0.f; }

  short8 ah[16], al[16];
  const int hrow  = t >> 3;
  const int cbase = (t & 7) * 32;
  float4 g4[8];

  auto issueG = [&](int step) {
    int wi = step >> 2, bi = step & 3;
    int w = wg * 8 + wi;
    int b = bg * 4 + bi;
    int n = idxp[((size_t)b * 256 + w) * 32 + hrow];
    const float* src = h3T + ((size_t)b * NPTS + n) * 256 + cbase;
#pragma unroll
    for (int j = 0; j < 8; ++j) g4[j] = *(const float4*)&src[j * 4];
  };
  auto writeG = [&](int buf) {
#pragma unroll
    for (int a = 0; a < 4; ++a) {
      int c8 = (cbase >> 3) + a;
      int ks = c8 >> 1;
      int lp = hrow + (c8 & 1) * 32;
      float4 v0 = g4[a * 2], v1 = g4[a * 2 + 1];
      uint32 u0 = (uint32)f2bf(v0.x) | ((uint32)f2bf(v0.y) << 16);
      uint32 u1 = (uint32)f2bf(v0.z) | ((uint32)f2bf(v0.w) << 16);
      uint32 u2 = (uint32)f2bf(v1.x) | ((uint32)f2bf(v1.y) << 16);
      uint32 u3 = (uint32)f2bf(v1.z) | ((uint32)f2bf(v1.w) << 16);
      *(uint4*)&G[buf][((size_t)ks * 64 + lp) * 8] = make_uint4(u0, u1, u2, u3);
    }
  };

  issueG(0); writeG(0);
  __syncthreads();

  for (int wi = 0; wi < 8; ++wi) {
    const int w = wg * 8 + wi;
    {
      const size_t base = (((size_t)w * 8 + mt) * 16) * 512 + (size_t)l * 8;
#pragma unroll
      for (int ks = 0; ks < 16; ++ks) {
        ah[ks] = *(const short8*)(w8h + base + ks * 512);
        al[ks] = *(const short8*)(w8l + base + ks * 512);
      }
    }
#pragma unroll
    for (int bi = 0; bi < 4; ++bi) {
      const int step = wi * 4 + bi;
      const int cur = bi & 1;
      if (step < 31) issueG(step + 1);
      const u16* Gc = G[cur];
#pragma unroll
      for (int ks = 0; ks < 16; ++ks) {
        short8 bf = *(const short8*)&Gc[((size_t)ks * 64 + l) * 8];
        accH[bi] = __builtin_amdgcn_mfma_f32_32x32x16_bf16(ah[ks], bf, accH[bi], 0, 0, 0);
        accL[bi] = __builtin_amdgcn_mfma_f32_32x32x16_bf16(al[ks], bf, accL[bi], 0, 0, 0);
      }
      if (step < 31) writeG(1 - cur);
      __syncthreads();
    }
  }

  const int h = l & 31;
  const int rbase = oq * 128 + wv * 32 + 4 * (l >> 5);
#pragma unroll
  for (int bi = 0; bi < 4; ++bi) {
    int b = bg * 4 + bi;
    float* dst = y8p + ((size_t)(wg * BATCH + b) * 256) * 32;
#pragma unroll
    for (int r = 0; r < 16; ++r) {
      int o = rbase + (r & 3) + 8 * (r >> 2);
      dst[(size_t)o * 32 + h] = accH[bi][r] + accL[bi][r];
    }
  }
}

// ---------------- y8 = b8 + fixed-order sum of 32 w-group partials
__global__ __launch_bounds__(256) void y8_reduce(const float* __restrict__ y8p,
                                                 const float* __restrict__ b8,
                                                 float* __restrict__ y8) {
  int i = blockIdx.x * 256 + threadIdx.x;
  float s = b8[(i >> 5) & 255];
#pragma unroll
  for (int p = 0; p < 32; ++p) s += y8p[(size_t)p * Y8N + i];
  y8[i] = s;
}

// ---------------- conv9
__global__ __launch_bounds__(256) void conv9_kernel(const float* __restrict__ y8,
                                                    const float* __restrict__ w9,
                                                    const float* __restrict__ b9,
                                                    float* __restrict__ y9) {
  const int o = blockIdx.x, b = blockIdx.y;
  const float* yb = y8 + (size_t)b * 8192;
  const float* wo = w9 + (size_t)o * 8192;
  float s = 0.f;
  for (int i = threadIdx.x * 4; i < 8192; i += 1024) {
    float4 v = *(const float4*)&yb[i];
    float4 u = *(const float4*)&wo[i];
    s += v.x * u.x + v.y * u.y + v.z * u.z + v.w * u.w;
  }
  for (int off = 32; off; off >>= 1) s += __shfl_down(s, off, 64);
  __shared__ float ls[4];
  const int wid = threadIdx.x >> 6;
  if ((threadIdx.x & 63) == 0) ls[wid] = s;
  __syncthreads();
  if (threadIdx.x == 0) y9[(size_t)b * 256 + o] = ls[0] + ls[1] + ls[2] + ls[3] + b9[o];
}

// ---------------- cvec[b,o] = sum_c w4[o,c] * y9[b,c]
__global__ __launch_bounds__(256) void cvec_kernel(const float* __restrict__ y9,
                                                   const float* __restrict__ w4,
                                                   float* __restrict__ cvec) {
  int tid = blockIdx.x * 256 + threadIdx.x;
  if (tid >= BATCH * 512) return;
  const int b = tid >> 9, o = tid & 511;
  const float* row = w4 + (size_t)o * 320;
  const float* yb  = y9 + (size_t)b * 256;
  float s = 0.f;
  for (int c = 0; c < 256; c += 4) {
    float4 u = *(const float4*)&row[c];
    s += u.x * yb[c] + u.y * yb[c + 1] + u.z * yb[c + 2] + u.w * yb[c + 3];
  }
  cvec[(size_t)b * 512 + o] = s;
}

// ---------------- small weight transpose (fp32 conv path)
__global__ __launch_bounds__(256) void transpose_w(const float* __restrict__ src,
                                                   float* __restrict__ dst,
                                                   int O, int Ctot, int cOff, int Csub) {
  int i = blockIdx.x * 256 + threadIdx.x;
  if (i >= O * Csub) return;
  int c = i / O, o = i - c * O;
  dst[(size_t)c * O + o] = src[(size_t)o * Ctot + cOff + c];
}

// ---------------- final tanh
__global__ __launch_bounds__(256) void tanh_out(const float* __restrict__ raw,
                                                float* __restrict__ out) {
  int i = blockIdx.x * 256 + threadIdx.x;
  if (i < BATCH * 3 * NPTS) out[i] = tanhf(raw[i]);
}

extern "C" void kernel_launch(void* const* d_in, const int* in_sizes, int n_in,
                              void* d_out, int out_size, void* d_ws, size_t ws_size,
                              hipStream_t stream) {
  (void)in_sizes; (void)n_in; (void)ws_size; (void)out_size;
  const float* x   = (const float*)d_in[0];
  const float* w1  = (const float*)d_in[1];
  const float* g1  = (const float*)d_in[3];
  const float* be1 = (const float*)d_in[4];
  const float* w2  = (const float*)d_in[5];
  const float* g2  = (const float*)d_in[7];
  const float* be2 = (const float*)d_in[8];
  const float* w3  = (const float*)d_in[9];
  const float* g3  = (const float*)d_in[11];
  const float* be3 = (const float*)d_in[12];
  const float* w4  = (const float*)d_in[13];
  const float* g4  = (const float*)d_in[15];
  const float* be4 = (const float*)d_in[16];
  const float* w5  = (const float*)d_in[17];
  const float* g5  = (const float*)d_in[19];
  const float* be5 = (const float*)d_in[20];
  const float* w6  = (const float*)d_in[21];
  const float* g6  = (const float*)d_in[23];
  const float* be6 = (const float*)d_in[24];
  const float* w7  = (const float*)d_in[25];
  const float* b7  = (const float*)d_in[26];
  const float* w8  = (const float*)d_in[27];
  const float* b8  = (const float*)d_in[28];
  const float* w9  = (const float*)d_in[29];
  const float* b9  = (const float*)d_in[30];

  char* ws = (char*)d_ws;
  size_t off = 0;
  auto alloc = [&](size_t bytes) -> void* {
    void* p = ws + off;
    off += (bytes + 255) & ~(size_t)255;
    return p;
  };
  float* Q1  = (float*)alloc((size_t)BATCH * 64  * NPTS * 4);  // h1 / raw7
  float* Q2  = (float*)alloc((size_t)BATCH * 128 * NPTS * 4);  // h2 / y8p / h4 base / h6
  float* Q3  = (float*)alloc((size_t)BATCH * 256 * NPTS * 4);  // h3 (raw)
  float* Q4  = (float*)alloc((size_t)BATCH * 256 * NPTS * 4);  // w8t (early) / h3T
  float* Q5  = (float*)alloc((size_t)BATCH * 256 * NPTS * 4);  // w8h+w8l (early) / h5
  int*   idx  = (int*)alloc((size_t)BATCH * 256 * 32 * 4);
  float* y8   = (float*)alloc((size_t)Y8N * 4);
  float* y9   = (float*)alloc((size_t)BATCH * 256 * 4);
  float* cvec = (float*)alloc((size_t)BATCH * 512 * 4);
  float* ps   = (float*)alloc((size_t)2 * BATCH * 512 * 64 * 4);
  float* scb  = (float*)alloc((size_t)6 * 1024 * 4);
  float* w1t  = (float*)alloc(4   * 64  * 4);
  float* w2t  = (float*)alloc(64  * 128 * 4);
  float* w3t  = (float*)alloc(128 * 256 * 4);
  float* w7t  = (float*)alloc(128 * 3   * 4);
  u16* ph4 = (u16*)alloc(512 * 64  * 2);  u16* pl4 = (u16*)alloc(512 * 64  * 2);
  u16* ph5 = (u16*)alloc(256 * 512 * 2);  u16* pl5 = (u16*)alloc(256 * 512 * 2);
  u16* ph6 = (u16*)alloc(128 * 256 * 2);  u16* pl6 = (u16*)alloc(128 * 256 * 2);

  float* w8t = Q4;                            // fp32, dead before h3T
  u16*   w8h = (u16*)Q5;                      // 33.5MB
  u16*   w8l = (u16*)Q5 + (size_t)16777216;   // dead before h5
  float* y8p = Q2;                            // dead before h4
  float* h4  = Q2;                            // 134MB spans Q2..Q4 head (all dead then)

  float* sc[6]; float* sh[6];
  for (int i = 0; i < 6; ++i) { sc[i] = scb + i * 1024; sh[i] = scb + i * 1024 + 512; }

  // ---- weight preprocessing
  transpose_w<<<(4 * 64 + 255) / 256,   256, 0, stream>>>(w1, w1t, 64, 4, 0, 4);
  transpose_w<<<(64 * 128 + 255) / 256, 256, 0, stream>>>(w2, w2t, 128, 64, 0, 64);
  transpose_w<<<(128 * 256 + 255) / 256,256, 0, stream>>>(w3, w3t, 256, 128, 0, 128);
  transpose_w<<<(128 * 3 + 255) / 256,  256, 0, stream>>>(w7, w7t, 3, 128, 0, 128);
  pack_wmfma<<<(512 * 64  + 255) / 256, 256, 0, stream>>>(w4, ph4, pl4, 512, 320, 256, 64);
  pack_wmfma<<<(256 * 512 + 255) / 256, 256, 0, stream>>>(w5, ph5, pl5, 256, 512, 0,   512);
  pack_wmfma<<<(128 * 256 + 255) / 256, 256, 0, stream>>>(w6, ph6, pl6, 128, 256, 0,   256);
  transpose_w8<<<dim3(1024, 4), 256, 0, stream>>>(w8, w8t);
  pack_w8<<<65536, 256, 0, stream>>>(w8t, w8h, w8l);

  // ---- conv1..3 fp32 (topk-feeding chain: fp32 accuracy required for rank stability)
  conv_gemm<<<dim3(64, 1, BATCH), 256, 0, stream>>>(x, w1t, nullptr, nullptr, nullptr, nullptr, Q1, ps, 4, 64);
  bn_finalize<<<64, 256, 0, stream>>>(ps, g1, be1, sc[0], sh[0], 64, 64);
  conv_gemm<<<dim3(64, 2, BATCH), 256, 0, stream>>>(Q1, w2t, nullptr, nullptr, sc[0], sh[0], Q2, ps, 64, 128);
  bn_finalize<<<128, 256, 0, stream>>>(ps, g2, be2, sc[1], sh[1], 128, 64);
  conv_gemm<<<dim3(64, 4, BATCH), 256, 0, stream>>>(Q2, w3t, nullptr, nullptr, sc[1], sh[1], Q3, ps, 128, 256);
  bn_finalize<<<256, 256, 0, stream>>>(ps, g3, be3, sc[2], sh[2], 256, 64);

  // ---- softpool
  topk_kernel<<<dim3(256, BATCH), 256, 0, stream>>>(Q3, idx);
  transpose_h3<<<dim3(NPTS / 32, 8, BATCH), 256, 0, stream>>>(Q3, Q4, sc[2], sh[2]);

  // ---- conv8 -> conv9 -> cvec
  conv8_mfma<<<dim3(32, 2, 4), 256, 0, stream>>>(Q4, w8h, w8l, idx, y8p);
  y8_reduce<<<Y8N / 256, 256, 0, stream>>>(y8p, b8, y8);
  conv9_kernel<<<dim3(256, BATCH), 256, 0, stream>>>(y8, w9, b9, y9);
  cvec_kernel<<<(BATCH * 512 + 255) / 256, 256, 0, stream>>>(y9, w4, cvec);

  // ---- conv4 (MFMA, rowbias=cvec, input h1 raw + BN1+relu)
  conv_mfma<<<dim3(32, 4, BATCH), 256, 0, stream>>>(Q1, ph4, pl4, cvec, sc[0], sh[0], h4, ps, 64, 512);
  bn_finalize<<<512, 256, 0, stream>>>(ps, g4, be4, sc[3], sh[3], 512, 32);
  // ---- conv5 (MFMA)
  conv_mfma<<<dim3(32, 2, BATCH), 256, 0, stream>>>(h4, ph5, pl5, nullptr, sc[3], sh[3], Q5, ps, 512, 256);
  bn_finalize<<<256, 256, 0, stream>>>(ps, g5, be5, sc[4], sh[4], 256, 32);
  // ---- conv6 (MFMA)
  conv_mfma<<<dim3(32, 1, BATCH), 256, 0, stream>>>(Q5, ph6, pl6, nullptr, sc[4], sh[4], Q2, ps, 256, 128);
  bn_finalize<<<128, 256, 0, stream>>>(ps, g6, be6, sc[5], sh[5], 128, 32);
  // ---- conv7 (fp32, +b7, fused BN6+relu) -> tanh
  conv_gemm<<<dim3(64, 1, BATCH), 256, 0, stream>>>(Q2, w7t, nullptr, b7, sc[5], sh[5], Q1, nullptr, 128, 3);
  tanh_out<<<(BATCH * 3 * NPTS) / 256, 256, 0, stream>>>(Q1, (float*)d_out);
}

// Round 9
// 763.625 us; speedup vs baseline: 2.0461x; 1.0261x over previous
//
#include <hip/hip_runtime.h>
#include <cstdint>
#include <cstddef>

#define NPTS 4096
#define BATCH 16

typedef unsigned int uint32;
typedef unsigned short u16;

typedef __attribute__((ext_vector_type(8))) short short8;
typedef __attribute__((ext_vector_type(16))) float float16;

__device__ __forceinline__ u16 f2bf(float f) {
  uint32 u = __float_as_uint(f);
  u = (u + 0x7fffu + ((u >> 16) & 1u)) >> 16;
  return (u16)u;
}
__device__ __forceinline__ float bf2f(u16 h) {
  return __uint_as_float(((uint32)h) << 16);
}

// ---------------- fp32 1x1-conv GEMM (conv1..3, conv7) — FROZEN bit-exact (R7 basin).
// Any numeric change here re-rolls the topk rank-flip die (R8 post-mortem). Do not touch.
__global__ __launch_bounds__(256) void conv_gemm(
    const float* __restrict__ act, const float* __restrict__ wt,
    const float* __restrict__ rowbias, const float* __restrict__ obias,
    const float* __restrict__ inScale, const float* __restrict__ inShift,
    float* __restrict__ out, float* __restrict__ partials, int C, int O)
{
  __shared__ float As[16][68];
  __shared__ float Ws[16][68];
  __shared__ float redS[64][17];
  __shared__ float redQ[64][17];
  const int b  = blockIdx.z;
  const int o0 = blockIdx.y * 64;
  const int n0 = blockIdx.x * 64;
  const int t  = threadIdx.x;
  const int tx = t & 15, ty = t >> 4;
  float acc[4][4] = {};
  const float* actb = act + ((size_t)b * C) * NPTS;

  for (int k0 = 0; k0 < C; k0 += 16) {
    const int r  = ty;
    const int cs = tx * 4;
    const int k  = k0 + r;
    float4 av = make_float4(0.f, 0.f, 0.f, 0.f);
    if (k < C) {
      av = *(const float4*)(actb + (size_t)k * NPTS + n0 + cs);
      if (inScale) {
        const float scv = inScale[k], shv = inShift[k];
        av.x = fmaxf(fmaf(av.x, scv, shv), 0.f);
        av.y = fmaxf(fmaf(av.y, scv, shv), 0.f);
        av.z = fmaxf(fmaf(av.z, scv, shv), 0.f);
        av.w = fmaxf(fmaf(av.w, scv, shv), 0.f);
      }
    }
    *(float4*)&As[r][cs] = av;

    float4 wv = make_float4(0.f, 0.f, 0.f, 0.f);
    if (k < C) {
      const float* wp = wt + (size_t)k * O;
      const int o = o0 + cs;
      if (o + 3 < O) {
        wv = *(const float4*)&wp[o];
      } else {
        float tmp[4] = {0.f, 0.f, 0.f, 0.f};
        for (int j = 0; j < 4; ++j) if (o + j < O) tmp[j] = wp[o + j];
        wv = make_float4(tmp[0], tmp[1], tmp[2], tmp[3]);
      }
    }
    *(float4*)&Ws[r][cs] = wv;
    __syncthreads();

    const int kmax = (C - k0 < 16) ? (C - k0) : 16;
    for (int kk = 0; kk < kmax; ++kk) {
      float4 a = *(float4*)&As[kk][tx * 4];
      float4 w = *(float4*)&Ws[kk][ty * 4];
      acc[0][0] += w.x * a.x; acc[0][1] += w.x * a.y; acc[0][2] += w.x * a.z; acc[0][3] += w.x * a.w;
      acc[1][0] += w.y * a.x; acc[1][1] += w.y * a.y; acc[1][2] += w.y * a.z; acc[1][3] += w.y * a.w;
      acc[2][0] += w.z * a.x; acc[2][1] += w.z * a.y; acc[2][2] += w.z * a.z; acc[2][3] += w.z * a.w;
      acc[3][0] += w.w * a.x; acc[3][1] += w.w * a.y; acc[3][2] += w.w * a.z; acc[3][3] += w.w * a.w;
    }
    __syncthreads();
  }

  float s[4], q[4];
  for (int i = 0; i < 4; ++i) {
    const int o = o0 + ty * 4 + i;
    s[i] = 0.f; q[i] = 0.f;
    if (o >= O) continue;
    float base = 0.f;
    if (rowbias) base  = rowbias[(size_t)b * O + o];
    if (obias)   base += obias[o];
    float4 v = make_float4(acc[i][0] + base, acc[i][1] + base, acc[i][2] + base, acc[i][3] + base);
    *(float4*)&out[((size_t)b * O + o) * NPTS + n0 + tx * 4] = v;
    s[i] = v.x + v.y + v.z + v.w;
    q[i] = v.x * v.x + v.y * v.y + v.z * v.z + v.w * v.w;
  }

  if (partials) {
    for (int i = 0; i < 4; ++i) { redS[ty * 4 + i][tx] = s[i]; redQ[ty * 4 + i][tx] = q[i]; }
    __syncthreads();
    if (t < 64) {
      float a = 0.f;
      for (int j = 0; j < 16; ++j) a += redS[t][j];
      partials[((size_t)b * O + o0 + t) * 64 + blockIdx.x] = a;
    } else if (t < 128) {
      float a = 0.f;
      for (int j = 0; j < 16; ++j) a += redQ[t - 64][j];
      partials[(size_t)BATCH * O * 64 + ((size_t)b * O + o0 + t - 64) * 64 + blockIdx.x] = a;
    }
  }
}

// ---------------- pack weights (O,Ctot) fp32 -> hi/lo bf16 A-frag order
__global__ __launch_bounds__(256) void pack_wmfma(const float* __restrict__ src,
                                                  u16* __restrict__ ph, u16* __restrict__ pl,
                                                  int O, int Ctot, int cOff, int Csub) {
  int i = blockIdx.x * 256 + threadIdx.x;
  if (i >= O * Csub) return;
  const int KS = Csub >> 4;
  int j    = i & 7;
  int lj   = (i >> 3) & 63;
  int mtks = i >> 9;
  int ks   = mtks % KS;
  int mt   = mtks / KS;
  int o = mt * 32 + (lj & 31);
  int c = ks * 16 + (lj >> 5) * 8 + j;
  float v = src[(size_t)o * Ctot + cOff + c];
  u16 h = f2bf(v);
  ph[i] = h;
  pl[i] = f2bf(v - bf2f(h));
}

// ---------------- MFMA 1x1-conv GEMM (conv4/5/6): 128o x 128n tile, split-bf16,
// DOUBLE-BUFFERED LDS staging, one barrier per 32-c chunk (R7 had 2 barriers +
// exposed global latency -> MfmaUtil 17%).
__global__ __launch_bounds__(256) void conv_mfma(
    const float* __restrict__ act, const u16* __restrict__ wh, const u16* __restrict__ wl,
    const float* __restrict__ rowbias,
    const float* __restrict__ inScale, const float* __restrict__ inShift,
    float* __restrict__ out, float* __restrict__ ps, int C, int O)
{
  __shared__ u16 Bh[2][4096];
  __shared__ u16 Bl[2][4096];
  const int b  = blockIdx.z;
  const int o0 = blockIdx.y * 128;
  const int n0 = blockIdx.x * 128;
  const int t  = threadIdx.x;
  const int l  = t & 63, wva = t >> 6;
  const int mt = blockIdx.y * 4 + wva;
  const int KS = C >> 4;
  const int NCH = C >> 5;
  const float* actb = act + ((size_t)b * C) * NPTS;

  float16 acc[4];
#pragma unroll
  for (int ns = 0; ns < 4; ++ns)
#pragma unroll
    for (int r = 0; r < 16; ++r) acc[ns][r] = 0.f;

  const int cq = t >> 5;
  const int nq = t & 31;
  const int nn = n0 + nq * 4;
  const int ksl = cq >> 2, oct = (cq >> 1) & 1, j0 = (cq & 1) * 4;

  float va[4][4];
  float4 scv = make_float4(1.f,1.f,1.f,1.f), shv = make_float4(0.f,0.f,0.f,0.f);

  auto loadChunk = [&](int ch) {
    const int cb = ch * 32 + cq * 4;
#pragma unroll
    for (int i2 = 0; i2 < 4; ++i2) {
      float4 v4 = *(const float4*)(actb + (size_t)(cb + i2) * NPTS + nn);
      va[i2][0] = v4.x; va[i2][1] = v4.y; va[i2][2] = v4.z; va[i2][3] = v4.w;
    }
    if (inScale) {
      scv = *(const float4*)&inScale[cb];
      shv = *(const float4*)&inShift[cb];
    }
  };
  auto applyBN = [&]() {
    if (!inScale) return;
#pragma unroll
    for (int d = 0; d < 4; ++d) {
      va[0][d] = fmaxf(fmaf(va[0][d], scv.x, shv.x), 0.f);
      va[1][d] = fmaxf(fmaf(va[1][d], scv.y, shv.y), 0.f);
      va[2][d] = fmaxf(fmaf(va[2][d], scv.z, shv.z), 0.f);
      va[3][d] = fmaxf(fmaf(va[3][d], scv.w, shv.w), 0.f);
    }
  };
  auto convWrite = [&](int buf) {
#pragma unroll
    for (int d = 0; d < 4; ++d) {
      const int nrel = nq * 4 + d;
      const int ns = nrel >> 5, li = nrel & 31;
      u16 h0 = f2bf(va[0][d]), h1 = f2bf(va[1][d]), h2 = f2bf(va[2][d]), h3 = f2bf(va[3][d]);
      u16 q0 = f2bf(va[0][d] - bf2f(h0));
      u16 q1 = f2bf(va[1][d] - bf2f(h1));
      u16 q2 = f2bf(va[2][d] - bf2f(h2));
      u16 q3 = f2bf(va[3][d] - bf2f(h3));
      const int idx = ((ksl * 4 + ns) * 64 + oct * 32 + li) * 8 + j0;
      *(ushort4*)&Bh[buf][idx] = make_ushort4(h0, h1, h2, h3);
      *(ushort4*)&Bl[buf][idx] = make_ushort4(q0, q1, q2, q3);
    }
  };

  loadChunk(0);
  applyBN();
  convWrite(0);
  __syncthreads();

  for (int ch = 0; ch < NCH; ++ch) {
    const size_t abase = (((size_t)mt * KS + ch * 2) * 64 + (size_t)l) * 8;
    short8 AH0 = *(const short8*)(wh + abase);
    short8 AH1 = *(const short8*)(wh + abase + 512);
    short8 AL0 = *(const short8*)(wl + abase);
    short8 AL1 = *(const short8*)(wl + abase + 512);
    const bool more = (ch + 1 < NCH);
    if (more) loadChunk(ch + 1);   // global loads in flight during MFMA phase

    const u16* bh = Bh[ch & 1];
    const u16* bl = Bl[ch & 1];
#pragma unroll
    for (int ns = 0; ns < 4; ++ns) {
      short8 BH0 = *(const short8*)&bh[((0 * 4 + ns) * 64 + l) * 8];
      short8 BL0 = *(const short8*)&bl[((0 * 4 + ns) * 64 + l) * 8];
      acc[ns] = __builtin_amdgcn_mfma_f32_32x32x16_bf16(AL0, BH0, acc[ns], 0, 0, 0);
      acc[ns] = __builtin_amdgcn_mfma_f32_32x32x16_bf16(AH0, BL0, acc[ns], 0, 0, 0);
      acc[ns] = __builtin_amdgcn_mfma_f32_32x32x16_bf16(AH0, BH0, acc[ns], 0, 0, 0);
      short8 BH1 = *(const short8*)&bh[((4 + ns) * 64 + l) * 8];
      short8 BL1 = *(const short8*)&bl[((4 + ns) * 64 + l) * 8];
      acc[ns] = __builtin_amdgcn_mfma_f32_32x32x16_bf16(AL1, BH1, acc[ns], 0, 0, 0);
      acc[ns] = __builtin_amdgcn_mfma_f32_32x32x16_bf16(AH1, BL1, acc[ns], 0, 0, 0);
      acc[ns] = __builtin_amdgcn_mfma_f32_32x32x16_bf16(AH1, BH1, acc[ns], 0, 0, 0);
    }
    if (more) { applyBN(); convWrite((ch + 1) & 1); }
    __syncthreads();
  }

  const int col = l & 31, half = l >> 5;
  float sv[16], sq[16];
#pragma unroll
  for (int r = 0; r < 16; ++r) {
    const int o = o0 + wva * 32 + (r & 3) + 8 * (r >> 2) + 4 * half;
    const float base = rowbias ? rowbias[(size_t)b * O + o] : 0.f;
    float s = 0.f, q = 0.f;
#pragma unroll
    for (int ns = 0; ns < 4; ++ns) {
      float val = acc[ns][r] + base;
      out[((size_t)b * O + o) * NPTS + n0 + ns * 32 + col] = val;
      s += val; q += val * val;
    }
    sv[r] = s; sq[r] = q;
  }
  if (ps) {
#pragma unroll
    for (int r = 0; r < 16; ++r) {
#pragma unroll
      for (int m = 1; m < 32; m <<= 1) {
        sv[r] += __shfl_xor(sv[r], m, 64);
        sq[r] += __shfl_xor(sq[r], m, 64);
      }
    }
    if (col == 0) {
#pragma unroll
      for (int r = 0; r < 16; ++r) {
        const int o = o0 + wva * 32 + (r & 3) + 8 * (r >> 2) + 4 * half;
        ps[((size_t)b * O + o) * 32 + blockIdx.x] = sv[r];
        ps[(size_t)BATCH * O * 32 + ((size_t)b * O + o) * 32 + blockIdx.x] = sq[r];
      }
    }
  }
}

// ---------------- BN finalize: one block per channel, parallel deterministic reduction
__global__ __launch_bounds__(256) void bn_finalize(const float* __restrict__ ps,
                                                   const float* __restrict__ g, const float* __restrict__ be,
                                                   float* __restrict__ scale, float* __restrict__ shift,
                                                   int O, int NT) {
  const int c = blockIdx.x;
  const int total = BATCH * NT;
  const float* p2 = ps + (size_t)BATCH * O * NT;
  const int t = threadIdx.x;
  float s = 0.f, q = 0.f;
  for (int e = t; e < total; e += 256) {
    const int b = e / NT, nt = e - b * NT;
    const size_t a = ((size_t)b * O + c) * NT + nt;
    s += ps[a];
    q += p2[a];
  }
#pragma unroll
  for (int m = 32; m; m >>= 1) {
    s += __shfl_down(s, m, 64);
    q += __shfl_down(q, m, 64);
  }
  __shared__ float lsS[4], lsQ[4];
  const int wid = t >> 6;
  if ((t & 63) == 0) { lsS[wid] = s; lsQ[wid] = q; }
  __syncthreads();
  if (t == 0) {
    s = lsS[0] + lsS[1] + lsS[2] + lsS[3];
    q = lsQ[0] + lsQ[1] + lsQ[2] + lsQ[3];
    const float inv = 1.f / 65536.f;
    float m   = s * inv;
    float var = q * inv - m * m;
    float sc  = g[c] * rsqrtf(var + 1e-5f);
    scale[c] = sc;
    shift[c] = be[c] - m * sc;
  }
}

// ---------------- top-32 per (b,c) on RAW h3: register tournament (deterministic)
__global__ __launch_bounds__(256) void topk_kernel(const float* __restrict__ h3,
                                                   int* __restrict__ idxp) {
  __shared__ float wvv[4];
  __shared__ int   wvi[4];
  __shared__ int   bcI;
  const int c = blockIdx.x, b = blockIdx.y;
  const float* src = h3 + ((size_t)b * 256 + c) * NPTS;
  const int t = threadIdx.x;
  float v[16];
  float bv = -INFINITY; int bi = NPTS;
#pragma unroll
  for (int s = 0; s < 16; ++s) {
    v[s] = src[t + 256 * s];
    if (v[s] > bv) { bv = v[s]; bi = t + 256 * s; }
  }
  int* dst = idxp + ((size_t)b * 256 + c) * 32;
  for (int r = 0; r < 32; ++r) {
    float rv = bv; int ri = bi;
#pragma unroll
    for (int off = 32; off; off >>= 1) {
      float ov = __shfl_down(rv, off, 64);
      int   oi = __shfl_down(ri, off, 64);
      if (ov > rv || (ov == rv && oi < ri)) { rv = ov; ri = oi; }
    }
    if ((t & 63) == 0) { wvv[t >> 6] = rv; wvi[t >> 6] = ri; }
    __syncthreads();
    if (t == 0) {
      for (int k = 1; k < 4; ++k)
        if (wvv[k] > rv || (wvv[k] == rv && wvi[k] < ri)) { rv = wvv[k]; ri = wvi[k]; }
      dst[r] = ri;
      bcI = ri;
    }
    __syncthreads();
    const int wi_ = bcI;
    if ((wi_ & 255) == t) {
      const int slot = wi_ >> 8;
#pragma unroll
      for (int s = 0; s < 16; ++s) if (s == slot) v[s] = -INFINITY;
      bv = -INFINITY; bi = NPTS;
#pragma unroll
      for (int s = 0; s < 16; ++s) if (v[s] > bv) { bv = v[s]; bi = t + 256 * s; }
    }
  }
}

// ---------------- transpose h3 (B,C,N) -> h3T (B,N,C), applying BN scale/shift
__global__ __launch_bounds__(256) void transpose_h3(const float* __restrict__ h3,
                                                    float* __restrict__ h3T,
                                                    const float* __restrict__ sc,
                                                    const float* __restrict__ sh) {
  __shared__ float tile[32][33];
  const int b = blockIdx.z;
  const int n0 = blockIdx.x * 32, c0 = blockIdx.y * 32;
  const int tx = threadIdx.x & 31, ty = threadIdx.x >> 5;
  const float* src = h3 + (size_t)b * 256 * NPTS;
  for (int j = 0; j < 4; ++j)
    tile[ty + j * 8][tx] = src[(size_t)(c0 + ty + j * 8) * NPTS + n0 + tx];
  __syncthreads();
  float* dst = h3T + (size_t)b * NPTS * 256;
  const float scv = sc[c0 + tx], shv = sh[c0 + tx];
  for (int j = 0; j < 4; ++j)
    dst[(size_t)(n0 + ty + j * 8) * 256 + c0 + tx] = fmaf(tile[tx][ty + j * 8], scv, shv);
}

// ---------------- fused: w8 (o,c,w) -> hi/lo bf16 directly in MFMA A-frag order
// (replaces transpose_w8 + pack_w8; removes the 134 MB fp32 w8t round-trip)
__global__ __launch_bounds__(256) void transpack_w8(const float* __restrict__ w8,
                                                    u16* __restrict__ w8h, u16* __restrict__ w8l) {
  __shared__ float tile[64][65];
  const int m0 = blockIdx.x * 64, w0 = blockIdx.y * 64;
  const int tx = threadIdx.x & 63, ty = threadIdx.x >> 6;
#pragma unroll
  for (int j = 0; j < 16; ++j)
    tile[ty + j * 4][tx] = w8[(size_t)(m0 + ty + j * 4) * 256 + w0 + tx];
  __syncthreads();
  const int m = m0 + tx;
  const int o = m >> 8, c = m & 255;
  const int mt = (o >> 5) & 7;
  const int lane = (o & 31) + ((c >> 3) & 1) * 32;
  const int ks = (c >> 4) & 15;
  const int jj = c & 7;
#pragma unroll
  for (int j = 0; j < 16; ++j) {
    const int w = w0 + ty + j * 4;
    float v = tile[tx][ty + j * 4];
    size_t f = ((((size_t)w * 8 + mt) * 16 + ks) * 64 + lane) * 8 + jj;
    u16 h = f2bf(v);
    w8h[f] = h;
    w8l[f] = f2bf(v - bf2f(h));
  }
}

// ---------------- conv8 via MFMA (verified in R4)
#define Y8N (BATCH * 256 * 32)
__global__ __launch_bounds__(256, 1) void conv8_mfma(
    const float* __restrict__ h3T, const u16* __restrict__ w8h,
    const u16* __restrict__ w8l, const int* __restrict__ idxp,
    float* __restrict__ y8p)
{
  __shared__ u16 G[2][8192];
  const int wg = blockIdx.x;
  const int oq = blockIdx.y;
  const int bg = blockIdx.z;
  const int t  = threadIdx.x;
  const int l  = t & 63, wv = t >> 6;
  const int mt = oq * 4 + wv;

  float16 accH[4], accL[4];
  for (int i = 0; i < 4; ++i)
    for (int r = 0; r < 16; ++r) { accH[i][r] = 0.f; accL[i][r] = 0.f; }

  short8 ah[16], al[16];
  const int hrow  = t >> 3;
  const int cbase = (t & 7) * 32;
  float4 g4[8];

  auto issueG = [&](int step) {
    int wi = step >> 2, bi = step & 3;
    int w = wg * 8 + wi;
    int b = bg * 4 + bi;
    int n = idxp[((size_t)b * 256 + w) * 32 + hrow];
    const float* src = h3T + ((size_t)b * NPTS + n) * 256 + cbase;
#pragma unroll
    for (int j = 0; j < 8; ++j) g4[j] = *(const float4*)&src[j * 4];
  };
  auto writeG = [&](int buf) {
#pragma unroll
    for (int a = 0; a < 4; ++a) {
      int c8 = (cbase >> 3) + a;
      int ks = c8 >> 1;
      int lp = hrow + (c8 & 1) * 32;
      float4 v0 = g4[a * 2], v1 = g4[a * 2 + 1];
      uint32 u0 = (uint32)f2bf(v0.x) | ((uint32)f2bf(v0.y) << 16);
      uint32 u1 = (uint32)f2bf(v0.z) | ((uint32)f2bf(v0.w) << 16);
      uint32 u2 = (uint32)f2bf(v1.x) | ((uint32)f2bf(v1.y) << 16);
      uint32 u3 = (uint32)f2bf(v1.z) | ((uint32)f2bf(v1.w) << 16);
      *(uint4*)&G[buf][((size_t)ks * 64 + lp) * 8] = make_uint4(u0, u1, u2, u3);
    }
  };

  issueG(0); writeG(0);
  __syncthreads();

  for (int wi = 0; wi < 8; ++wi) {
    const int w = wg * 8 + wi;
    {
      const size_t base = (((size_t)w * 8 + mt) * 16) * 512 + (size_t)l * 8;
#pragma unroll
      for (int ks = 0; ks < 16; ++ks) {
        ah[ks] = *(const short8*)(w8h + base + ks * 512);
        al[ks] = *(const short8*)(w8l + base + ks * 512);
      }
    }
#pragma unroll
    for (int bi = 0; bi < 4; ++bi) {
      const int step = wi * 4 + bi;
      const int cur = bi & 1;
      if (step < 31) issueG(step + 1);
      const u16* Gc = G[cur];
#pragma unroll
      for (int ks = 0; ks < 16; ++ks) {
        short8 bf = *(const short8*)&Gc[((size_t)ks * 64 + l) * 8];
        accH[bi] = __builtin_amdgcn_mfma_f32_32x32x16_bf16(ah[ks], bf, accH[bi], 0, 0, 0);
        accL[bi] = __builtin_amdgcn_mfma_f32_32x32x16_bf16(al[ks], bf, accL[bi], 0, 0, 0);
      }
      if (step < 31) writeG(1 - cur);
      __syncthreads();
    }
  }

  const int h = l & 31;
  const int rbase = oq * 128 + wv * 32 + 4 * (l >> 5);
#pragma unroll
  for (int bi = 0; bi < 4; ++bi) {
    int b = bg * 4 + bi;
    float* dst = y8p + ((size_t)(wg * BATCH + b) * 256) * 32;
#pragma unroll
    for (int r = 0; r < 16; ++r) {
      int o = rbase + (r & 3) + 8 * (r >> 2);
      dst[(size_t)o * 32 + h] = accH[bi][r] + accL[bi][r];
    }
  }
}

// ---------------- y8 = b8 + fixed-order sum of 32 w-group partials
__global__ __launch_bounds__(256) void y8_reduce(const float* __restrict__ y8p,
                                                 const float* __restrict__ b8,
                                                 float* __restrict__ y8) {
  int i = blockIdx.x * 256 + threadIdx.x;
  float s = b8[(i >> 5) & 255];
#pragma unroll
  for (int p = 0; p < 32; ++p) s += y8p[(size_t)p * Y8N + i];
  y8[i] = s;
}

// ---------------- conv9
__global__ __launch_bounds__(256) void conv9_kernel(const float* __restrict__ y8,
                                                    const float* __restrict__ w9,
                                                    const float* __restrict__ b9,
                                                    float* __restrict__ y9) {
  const int o = blockIdx.x, b = blockIdx.y;
  const float* yb = y8 + (size_t)b * 8192;
  const float* wo = w9 + (size_t)o * 8192;
  float s = 0.f;
  for (int i = threadIdx.x * 4; i < 8192; i += 1024) {
    float4 v = *(const float4*)&yb[i];
    float4 u = *(const float4*)&wo[i];
    s += v.x * u.x + v.y * u.y + v.z * u.z + v.w * u.w;
  }
  for (int off = 32; off; off >>= 1) s += __shfl_down(s, off, 64);
  __shared__ float ls[4];
  const int wid = threadIdx.x >> 6;
  if ((threadIdx.x & 63) == 0) ls[wid] = s;
  __syncthreads();
  if (threadIdx.x == 0) y9[(size_t)b * 256 + o] = ls[0] + ls[1] + ls[2] + ls[3] + b9[o];
}

// ---------------- cvec[b,o] = sum_c w4[o,c] * y9[b,c]
__global__ __launch_bounds__(256) void cvec_kernel(const float* __restrict__ y9,
                                                   const float* __restrict__ w4,
                                                   float* __restrict__ cvec) {
  int tid = blockIdx.x * 256 + threadIdx.x;
  if (tid >= BATCH * 512) return;
  const int b = tid >> 9, o = tid & 511;
  const float* row = w4 + (size_t)o * 320;
  const float* yb  = y9 + (size_t)b * 256;
  float s = 0.f;
  for (int c = 0; c < 256; c += 4) {
    float4 u = *(const float4*)&row[c];
    s += u.x * yb[c] + u.y * yb[c + 1] + u.z * yb[c + 2] + u.w * yb[c + 3];
  }
  cvec[(size_t)b * 512 + o] = s;
}

// ---------------- small weight transpose (fp32 conv path)
__global__ __launch_bounds__(256) void transpose_w(const float* __restrict__ src,
                                                   float* __restrict__ dst,
                                                   int O, int Ctot, int cOff, int Csub) {
  int i = blockIdx.x * 256 + threadIdx.x;
  if (i >= O * Csub) return;
  int c = i / O, o = i - c * O;
  dst[(size_t)c * O + o] = src[(size_t)o * Ctot + cOff + c];
}

// ---------------- final tanh
__global__ __launch_bounds__(256) void tanh_out(const float* __restrict__ raw,
                                                float* __restrict__ out) {
  int i = blockIdx.x * 256 + threadIdx.x;
  if (i < BATCH * 3 * NPTS) out[i] = tanhf(raw[i]);
}

extern "C" void kernel_launch(void* const* d_in, const int* in_sizes, int n_in,
                              void* d_out, int out_size, void* d_ws, size_t ws_size,
                              hipStream_t stream) {
  (void)in_sizes; (void)n_in; (void)ws_size; (void)out_size;
  const float* x   = (const float*)d_in[0];
  const float* w1  = (const float*)d_in[1];
  const float* g1  = (const float*)d_in[3];
  const float* be1 = (const float*)d_in[4];
  const float* w2  = (const float*)d_in[5];
  const float* g2  = (const float*)d_in[7];
  const float* be2 = (const float*)d_in[8];
  const float* w3  = (const float*)d_in[9];
  const float* g3  = (const float*)d_in[11];
  const float* be3 = (const float*)d_in[12];
  const float* w4  = (const float*)d_in[13];
  const float* g4  = (const float*)d_in[15];
  const float* be4 = (const float*)d_in[16];
  const float* w5  = (const float*)d_in[17];
  const float* g5  = (const float*)d_in[19];
  const float* be5 = (const float*)d_in[20];
  const float* w6  = (const float*)d_in[21];
  const float* g6  = (const float*)d_in[23];
  const float* be6 = (const float*)d_in[24];
  const float* w7  = (const float*)d_in[25];
  const float* b7  = (const float*)d_in[26];
  const float* w8  = (const float*)d_in[27];
  const float* b8  = (const float*)d_in[28];
  const float* w9  = (const float*)d_in[29];
  const float* b9  = (const float*)d_in[30];

  char* ws = (char*)d_ws;
  size_t off = 0;
  auto alloc = [&](size_t bytes) -> void* {
    void* p = ws + off;
    off += (bytes + 255) & ~(size_t)255;
    return p;
  };
  float* Q1  = (float*)alloc((size_t)BATCH * 64  * NPTS * 4);  // h1 / raw7
  float* Q2  = (float*)alloc((size_t)BATCH * 128 * NPTS * 4);  // h2 / y8p / h4 base / h6
  float* Q3  = (float*)alloc((size_t)BATCH * 256 * NPTS * 4);  // h3 (raw)
  float* Q4  = (float*)alloc((size_t)BATCH * 256 * NPTS * 4);  // h3T
  float* Q5  = (float*)alloc((size_t)BATCH * 256 * NPTS * 4);  // w8h+w8l (early) / h5
  int*   idx  = (int*)alloc((size_t)BATCH * 256 * 32 * 4);
  float* y8   = (float*)alloc((size_t)Y8N * 4);
  float* y9   = (float*)alloc((size_t)BATCH * 256 * 4);
  float* cvec = (float*)alloc((size_t)BATCH * 512 * 4);
  float* ps   = (float*)alloc((size_t)2 * BATCH * 512 * 64 * 4);
  float* scb  = (float*)alloc((size_t)6 * 1024 * 4);
  float* w1t  = (float*)alloc(4   * 64  * 4);
  float* w2t  = (float*)alloc(64  * 128 * 4);
  float* w3t  = (float*)alloc(128 * 256 * 4);
  float* w7t  = (float*)alloc(128 * 3   * 4);
  u16* ph4 = (u16*)alloc(512 * 64  * 2);  u16* pl4 = (u16*)alloc(512 * 64  * 2);
  u16* ph5 = (u16*)alloc(256 * 512 * 2);  u16* pl5 = (u16*)alloc(256 * 512 * 2);
  u16* ph6 = (u16*)alloc(128 * 256 * 2);  u16* pl6 = (u16*)alloc(128 * 256 * 2);

  u16*   w8h = (u16*)Q5;                      // 33.5MB
  u16*   w8l = (u16*)Q5 + (size_t)16777216;   // dead before h5
  float* y8p = Q2;                            // dead before h4
  float* h4  = Q2;                            // 134MB spans Q2..Q4 head (all dead then)

  float* sc[6]; float* sh[6];
  for (int i = 0; i < 6; ++i) { sc[i] = scb + i * 1024; sh[i] = scb + i * 1024 + 512; }

  // ---- weight preprocessing
  transpose_w<<<(4 * 64 + 255) / 256,   256, 0, stream>>>(w1, w1t, 64, 4, 0, 4);
  transpose_w<<<(64 * 128 + 255) / 256, 256, 0, stream>>>(w2, w2t, 128, 64, 0, 64);
  transpose_w<<<(128 * 256 + 255) / 256,256, 0, stream>>>(w3, w3t, 256, 128, 0, 128);
  transpose_w<<<(128 * 3 + 255) / 256,  256, 0, stream>>>(w7, w7t, 3, 128, 0, 128);
  pack_wmfma<<<(512 * 64  + 255) / 256, 256, 0, stream>>>(w4, ph4, pl4, 512, 320, 256, 64);
  pack_wmfma<<<(256 * 512 + 255) / 256, 256, 0, stream>>>(w5, ph5, pl5, 256, 512, 0,   512);
  pack_wmfma<<<(128 * 256 + 255) / 256, 256, 0, stream>>>(w6, ph6, pl6, 128, 256, 0,   256);
  transpack_w8<<<dim3(1024, 4), 256, 0, stream>>>(w8, w8h, w8l);

  // ---- conv1..3 fp32 (FROZEN topk chain, bit-exact R7)
  conv_gemm<<<dim3(64, 1, BATCH), 256, 0, stream>>>(x, w1t, nullptr, nullptr, nullptr, nullptr, Q1, ps, 4, 64);
  bn_finalize<<<64, 256, 0, stream>>>(ps, g1, be1, sc[0], sh[0], 64, 64);
  conv_gemm<<<dim3(64, 2, BATCH), 256, 0, stream>>>(Q1, w2t, nullptr, nullptr, sc[0], sh[0], Q2, ps, 64, 128);
  bn_finalize<<<128, 256, 0, stream>>>(ps, g2, be2, sc[1], sh[1], 128, 64);
  conv_gemm<<<dim3(64, 4, BATCH), 256, 0, stream>>>(Q2, w3t, nullptr, nullptr, sc[1], sh[1], Q3, ps, 128, 256);
  bn_finalize<<<256, 256, 0, stream>>>(ps, g3, be3, sc[2], sh[2], 256, 64);

  // ---- softpool
  topk_kernel<<<dim3(256, BATCH), 256, 0, stream>>>(Q3, idx);
  transpose_h3<<<dim3(NPTS / 32, 8, BATCH), 256, 0, stream>>>(Q3, Q4, sc[2], sh[2]);

  // ---- conv8 -> conv9 -> cvec
  conv8_mfma<<<dim3(32, 2, 4), 256, 0, stream>>>(Q4, w8h, w8l, idx, y8p);
  y8_reduce<<<Y8N / 256, 256, 0, stream>>>(y8p, b8, y8);
  conv9_kernel<<<dim3(256, BATCH), 256, 0, stream>>>(y8, w9, b9, y9);
  cvec_kernel<<<(BATCH * 512 + 255) / 256, 256, 0, stream>>>(y9, w4, cvec);

  // ---- conv4 (MFMA dbuf, rowbias=cvec, input h1 raw + BN1+relu)
  conv_mfma<<<dim3(32, 4, BATCH), 256, 0, stream>>>(Q1, ph4, pl4, cvec, sc[0], sh[0], h4, ps, 64, 512);
  bn_finalize<<<512, 256, 0, stream>>>(ps, g4, be4, sc[3], sh[3], 512, 32);
  // ---- conv5 (MFMA dbuf)
  conv_mfma<<<dim3(32, 2, BATCH), 256, 0, stream>>>(h4, ph5, pl5, nullptr, sc[3], sh[3], Q5, ps, 512, 256);
  bn_finalize<<<256, 256, 0, stream>>>(ps, g5, be5, sc[4], sh[4], 256, 32);
  // ---- conv6 (MFMA dbuf)
  conv_mfma<<<dim3(32, 1, BATCH), 256, 0, stream>>>(Q5, ph6, pl6, nullptr, sc[4], sh[4], Q2, ps, 256, 128);
  bn_finalize<<<128, 256, 0, stream>>>(ps, g6, be6, sc[5], sh[5], 128, 32);
  // ---- conv7 (fp32, +b7, fused BN6+relu) -> tanh
  conv_gemm<<<dim3(64, 1, BATCH), 256, 0, stream>>>(Q2, w7t, nullptr, b7, sc[5], sh[5], Q1, nullptr, 128, 3);
  tanh_out<<<(BATCH * 3 * NPTS) / 256, 256, 0, stream>>>(Q1, (float*)d_out);
}